// Round 1
// baseline (5690.578 us; speedup 1.0000x reference)
//
#include <hip/hip_runtime.h>
#include <math.h>

#define D_MODEL 1024
#define N_HEADS 16
#define D_HEAD  64
#define SEQ     2048
#define BATCH   2
#define M_TOT   (BATCH*SEQ)   // 4096
#define FFN_DIM 4096

// ---------------- LayerNorm: one block (256 thr) per row of 1024 ----------------
__global__ __launch_bounds__(256) void ln_kernel(const float* __restrict__ x,
    const float* __restrict__ w, const float* __restrict__ b,
    float* __restrict__ out) {
  int row = blockIdx.x;
  const float* xr = x + (size_t)row * D_MODEL;
  float* outr = out + (size_t)row * D_MODEL;
  float v[4];
  float s = 0.f;
  #pragma unroll
  for (int i = 0; i < 4; ++i) { v[i] = xr[threadIdx.x + i*256]; s += v[i]; }
  __shared__ float red[4];
  #pragma unroll
  for (int o = 32; o > 0; o >>= 1) s += __shfl_down(s, o, 64);
  int wave = threadIdx.x >> 6;
  if ((threadIdx.x & 63) == 0) red[wave] = s;
  __syncthreads();
  float mean = (red[0]+red[1]+red[2]+red[3]) * (1.f/D_MODEL);
  __syncthreads();
  float s2 = 0.f;
  #pragma unroll
  for (int i = 0; i < 4; ++i) { float d = v[i]-mean; s2 += d*d; }
  #pragma unroll
  for (int o = 32; o > 0; o >>= 1) s2 += __shfl_down(s2, o, 64);
  if ((threadIdx.x & 63) == 0) red[wave] = s2;
  __syncthreads();
  float var = (red[0]+red[1]+red[2]+red[3]) * (1.f/D_MODEL);
  float rs = rsqrtf(var + 1e-5f);
  #pragma unroll
  for (int i = 0; i < 4; ++i) {
    int c = threadIdx.x + i*256;
    outr[c] = (v[i]-mean)*rs*w[c] + b[c];
  }
}

__device__ inline float gelu_exact(float x) {
  return 0.5f * x * (1.f + erff(x * 0.70710678118654752f));
}

// ---------------- GEMM: C[m,n] = sum_k A[m,k] * Bt[n,k]  (+ epilogue) ------------
// EPI: 0 = plain, 1 = gelu(x + bias), 2 = + res, 3 = + bias + res
// M,N,K all multiples of 64/16 here -> no bounds checks.
template<int EPI>
__global__ __launch_bounds__(256) void gemm_bt(const float* __restrict__ A,
    const float* __restrict__ Bt, float* __restrict__ C,
    const float* __restrict__ bias, const float* __restrict__ res,
    int M, int N, int K) {
  __shared__ float As[64][17];
  __shared__ float Bs[64][17];
  int tid = threadIdx.x;
  int tx = tid & 15, ty = tid >> 4;
  int bm = blockIdx.y * 64, bn = blockIdx.x * 64;
  float acc[4][4] = {};
  int lr = tid >> 2;           // 0..63
  int lk = (tid & 3) * 4;      // 0,4,8,12
  const float* ap0 = A  + (size_t)(bm + lr)*K + lk;
  const float* bp0 = Bt + (size_t)(bn + lr)*K + lk;
  for (int k0 = 0; k0 < K; k0 += 16) {
    float4 av = *(const float4*)(ap0 + k0);
    float4 bv = *(const float4*)(bp0 + k0);
    As[lr][lk+0]=av.x; As[lr][lk+1]=av.y; As[lr][lk+2]=av.z; As[lr][lk+3]=av.w;
    Bs[lr][lk+0]=bv.x; Bs[lr][lk+1]=bv.y; Bs[lr][lk+2]=bv.z; Bs[lr][lk+3]=bv.w;
    __syncthreads();
    #pragma unroll
    for (int kk = 0; kk < 16; ++kk) {
      float a[4], bb[4];
      #pragma unroll
      for (int i = 0; i < 4; ++i) a[i] = As[ty*4+i][kk];
      #pragma unroll
      for (int j = 0; j < 4; ++j) bb[j] = Bs[tx*4+j][kk];
      #pragma unroll
      for (int i = 0; i < 4; ++i)
        #pragma unroll
        for (int j = 0; j < 4; ++j)
          acc[i][j] += a[i]*bb[j];
    }
    __syncthreads();
  }
  #pragma unroll
  for (int i = 0; i < 4; ++i) {
    int row = bm + ty*4 + i;
    #pragma unroll
    for (int j = 0; j < 4; ++j) {
      int col = bn + tx*4 + j;
      float v = acc[i][j];
      if (EPI == 1) v = gelu_exact(v + bias[col]);
      if (EPI == 2) v += res[(size_t)row*N + col];
      if (EPI == 3) v += bias[col] + res[(size_t)row*N + col];
      C[(size_t)row*N + col] = v;
    }
  }
}

// ---------------- Causal attention: one block (256 thr) per (b,h,q) -------------
// qkv layout: row m=(b*SEQ+n), 3072 cols = [q(0..1023) | k(1024..2047) | v(2048..3071)],
// within each: head h at h*64.
__global__ __launch_bounds__(256) void attn_kernel(const float* __restrict__ qkv,
    float* __restrict__ out) {
  int q = blockIdx.x;
  int h = blockIdx.y;
  int b = blockIdx.z;
  const size_t rs3 = 3*D_MODEL;
  const float* qptr = qkv + ((size_t)(b*SEQ + q))*rs3 + h*D_HEAD;
  const float* kbase = qkv + (size_t)b*SEQ*rs3 + D_MODEL   + h*D_HEAD;
  const float* vbase = qkv + (size_t)b*SEQ*rs3 + 2*D_MODEL + h*D_HEAD;
  __shared__ float qs[64];
  __shared__ float p[SEQ];
  __shared__ float redbuf[256];
  int tid = threadIdx.x;
  if (tid < 64) qs[tid] = qptr[tid];
  __syncthreads();
  int nk = q + 1;
  const float scale = 0.125f;  // 1/sqrt(64)
  float lmax = -INFINITY;
  for (int k = tid; k < nk; k += 256) {
    const float* kp = kbase + (size_t)k*rs3;
    float dot = 0.f;
    #pragma unroll
    for (int d = 0; d < 64; ++d) dot += qs[d]*kp[d];
    dot *= scale;
    p[k] = dot;
    lmax = fmaxf(lmax, dot);
  }
  redbuf[tid] = lmax; __syncthreads();
  for (int s = 128; s > 0; s >>= 1) {
    if (tid < s) redbuf[tid] = fmaxf(redbuf[tid], redbuf[tid+s]);
    __syncthreads();
  }
  float mx = redbuf[0];
  __syncthreads();
  float lsum = 0.f;
  for (int k = tid; k < nk; k += 256) { float e = __expf(p[k]-mx); p[k] = e; lsum += e; }
  redbuf[tid] = lsum; __syncthreads();
  for (int s = 128; s > 0; s >>= 1) {
    if (tid < s) redbuf[tid] += redbuf[tid+s];
    __syncthreads();
  }
  float inv = 1.f / redbuf[0];
  __syncthreads();
  int dh = tid & 63;
  int g  = tid >> 6;
  float acc = 0.f;
  for (int k = g; k < nk; k += 4) acc += p[k] * vbase[(size_t)k*rs3 + dh];
  redbuf[tid] = acc; __syncthreads();
  if (g == 0) {
    float r = redbuf[dh] + redbuf[64+dh] + redbuf[128+dh] + redbuf[192+dh];
    out[((size_t)(b*SEQ + q))*D_MODEL + h*D_HEAD + dh] = r * inv;
  }
}

extern "C" void kernel_launch(void* const* d_in, const int* in_sizes, int n_in,
                              void* d_out, int out_size, void* d_ws, size_t ws_size,
                              hipStream_t stream) {
  const float* x      = (const float*)d_in[0];
  const float* ln1_w  = (const float*)d_in[1];
  const float* ln1_b  = (const float*)d_in[2];
  const float* ln2_w  = (const float*)d_in[3];
  const float* ln2_b  = (const float*)d_in[4];
  const float* qkv_w  = (const float*)d_in[5];
  const float* o_w    = (const float*)d_in[6];
  const float* ffn_w1 = (const float*)d_in[7];
  const float* ffn_b1 = (const float*)d_in[8];
  const float* ffn_w2 = (const float*)d_in[9];
  const float* ffn_b2 = (const float*)d_in[10];
  float* out = (float*)d_out;
  float* ws  = (float*)d_ws;

  const size_t MD = (size_t)M_TOT * D_MODEL;      // 4M floats
  float* h    = ws;                               // [0, 4M)   ln1 out, later ln2 out
  float* attn = ws + MD;                          // [4M, 8M)
  float* x1   = ws + 2*MD;                        // [8M, 12M)
  float* qkv  = ws + 3*MD;                        // [12M, 24M) dead after attention
  float* ff   = ws + 3*MD;                        // [12M, 28M) reuses qkv region

  // 1. h = LN1(x)
  ln_kernel<<<M_TOT, 256, 0, stream>>>(x, ln1_w, ln1_b, h);
  // 2. qkv = h @ qkv_w.T        (4096 x 3072 x 1024)
  gemm_bt<0><<<dim3(3*D_MODEL/64, M_TOT/64), 256, 0, stream>>>(
      h, qkv_w, qkv, nullptr, nullptr, M_TOT, 3*D_MODEL, D_MODEL);
  // 3. attn = causal MHA(qkv)
  attn_kernel<<<dim3(SEQ, N_HEADS, BATCH), 256, 0, stream>>>(qkv, attn);
  // 4. x1 = x + attn @ o_w.T    (4096 x 1024 x 1024)
  gemm_bt<2><<<dim3(D_MODEL/64, M_TOT/64), 256, 0, stream>>>(
      attn, o_w, x1, nullptr, x, M_TOT, D_MODEL, D_MODEL);
  // 5. h = LN2(x1)
  ln_kernel<<<M_TOT, 256, 0, stream>>>(x1, ln2_w, ln2_b, h);
  // 6. ff = gelu(h @ ffn_w1.T + b1)   (4096 x 4096 x 1024)
  gemm_bt<1><<<dim3(FFN_DIM/64, M_TOT/64), 256, 0, stream>>>(
      h, ffn_w1, ff, ffn_b1, nullptr, M_TOT, FFN_DIM, D_MODEL);
  // 7. out = x1 + ff @ ffn_w2.T + b2  (4096 x 1024 x 4096)
  gemm_bt<3><<<dim3(D_MODEL/64, M_TOT/64), 256, 0, stream>>>(
      ff, ffn_w2, out, ffn_b2, x1, M_TOT, D_MODEL, FFN_DIM);
}

// Round 2
// 2751.514 us; speedup vs baseline: 2.0682x; 2.0682x over previous
//
#include <hip/hip_runtime.h>
#include <math.h>

#define D_MODEL 1024
#define N_HEADS 16
#define D_HEAD  64
#define SEQ     2048
#define BATCH   2
#define M_TOT   (BATCH*SEQ)   // 4096
#define FFN_DIM 4096

// ---------------- LayerNorm: one block (256 thr) per row of 1024 ----------------
__global__ __launch_bounds__(256) void ln_kernel(const float* __restrict__ x,
    const float* __restrict__ w, const float* __restrict__ b,
    float* __restrict__ out) {
  int row = blockIdx.x;
  const float* xr = x + (size_t)row * D_MODEL;
  float* outr = out + (size_t)row * D_MODEL;
  float v[4];
  float s = 0.f;
  #pragma unroll
  for (int i = 0; i < 4; ++i) { v[i] = xr[threadIdx.x + i*256]; s += v[i]; }
  __shared__ float red[4];
  #pragma unroll
  for (int o = 32; o > 0; o >>= 1) s += __shfl_down(s, o, 64);
  int wave = threadIdx.x >> 6;
  if ((threadIdx.x & 63) == 0) red[wave] = s;
  __syncthreads();
  float mean = (red[0]+red[1]+red[2]+red[3]) * (1.f/D_MODEL);
  __syncthreads();
  float s2 = 0.f;
  #pragma unroll
  for (int i = 0; i < 4; ++i) { float d = v[i]-mean; s2 += d*d; }
  #pragma unroll
  for (int o = 32; o > 0; o >>= 1) s2 += __shfl_down(s2, o, 64);
  if ((threadIdx.x & 63) == 0) red[wave] = s2;
  __syncthreads();
  float var = (red[0]+red[1]+red[2]+red[3]) * (1.f/D_MODEL);
  float rs = rsqrtf(var + 1e-5f);
  #pragma unroll
  for (int i = 0; i < 4; ++i) {
    int c = threadIdx.x + i*256;
    outr[c] = (v[i]-mean)*rs*w[c] + b[c];
  }
}

__device__ inline float gelu_exact(float x) {
  return 0.5f * x * (1.f + erff(x * 0.70710678118654752f));
}

// ---------------- GEMM: C[m,n] = sum_k A[m,k] * Bt[n,k]  (+ epilogue) ------------
// EPI: 0 = plain, 1 = gelu(x + bias), 2 = + res, 3 = + bias + res
template<int EPI>
__global__ __launch_bounds__(256) void gemm_bt(const float* __restrict__ A,
    const float* __restrict__ Bt, float* __restrict__ C,
    const float* __restrict__ bias, const float* __restrict__ res,
    int M, int N, int K) {
  __shared__ float As[64][17];
  __shared__ float Bs[64][17];
  int tid = threadIdx.x;
  int tx = tid & 15, ty = tid >> 4;
  int bm = blockIdx.y * 64, bn = blockIdx.x * 64;
  float acc[4][4] = {};
  int lr = tid >> 2;           // 0..63
  int lk = (tid & 3) * 4;      // 0,4,8,12
  const float* ap0 = A  + (size_t)(bm + lr)*K + lk;
  const float* bp0 = Bt + (size_t)(bn + lr)*K + lk;
  for (int k0 = 0; k0 < K; k0 += 16) {
    float4 av = *(const float4*)(ap0 + k0);
    float4 bv = *(const float4*)(bp0 + k0);
    As[lr][lk+0]=av.x; As[lr][lk+1]=av.y; As[lr][lk+2]=av.z; As[lr][lk+3]=av.w;
    Bs[lr][lk+0]=bv.x; Bs[lr][lk+1]=bv.y; Bs[lr][lk+2]=bv.z; Bs[lr][lk+3]=bv.w;
    __syncthreads();
    #pragma unroll
    for (int kk = 0; kk < 16; ++kk) {
      float a[4], bb[4];
      #pragma unroll
      for (int i = 0; i < 4; ++i) a[i] = As[ty*4+i][kk];
      #pragma unroll
      for (int j = 0; j < 4; ++j) bb[j] = Bs[tx*4+j][kk];
      #pragma unroll
      for (int i = 0; i < 4; ++i)
        #pragma unroll
        for (int j = 0; j < 4; ++j)
          acc[i][j] += a[i]*bb[j];
    }
    __syncthreads();
  }
  #pragma unroll
  for (int i = 0; i < 4; ++i) {
    int row = bm + ty*4 + i;
    #pragma unroll
    for (int j = 0; j < 4; ++j) {
      int col = bn + tx*4 + j;
      float v = acc[i][j];
      if (EPI == 1) v = gelu_exact(v + bias[col]);
      if (EPI == 2) v += res[(size_t)row*N + col];
      if (EPI == 3) v += bias[col] + res[(size_t)row*N + col];
      C[(size_t)row*N + col] = v;
    }
  }
}

// ---------------- Flash-style causal attention ----------------------------------
// One block (256 thr) per (q-tile of 64, head, batch). K/V tiles of 64 staged in
// LDS; S = Q*K^T and O += P*V as 64x64x64 register-tiled matmuls (4x4/thread).
// Online softmax: per-q-row m,l in registers, reduced across the 16 lanes that
// share a ty-row via __shfl_xor(..,16). P round-trips through the K LDS buffer.
__global__ __launch_bounds__(256) void attn_tile_kernel(
    const float* __restrict__ qkv, float* __restrict__ out) {
  __shared__ float Qs[64][68];
  __shared__ float Ks[64][68];   // reused as P after S is computed
  __shared__ float Vs[64][68];

  int qt = blockIdx.x;          // q-tile index, 0..31
  int h  = blockIdx.y;
  int b  = blockIdx.z;
  int tid = threadIdx.x;
  int tx = tid & 15, ty = tid >> 4;

  const size_t rs3 = 3*D_MODEL;
  const float* qbase = qkv + (size_t)b*SEQ*rs3 +             h*D_HEAD;
  const float* kbase = qkv + (size_t)b*SEQ*rs3 + D_MODEL   + h*D_HEAD;
  const float* vbase = qkv + (size_t)b*SEQ*rs3 + 2*D_MODEL + h*D_HEAD;

  // Stage Q tile (scaled by 1/sqrt(64)) : 64 rows x 64 cols, 4 float4 per thread
  const float scale = 0.125f;
  #pragma unroll
  for (int i = 0; i < 4; ++i) {
    int idx = tid + i*256;
    int r = idx >> 4, c4 = (idx & 15) * 4;
    float4 v = *(const float4*)(qbase + (size_t)(qt*64 + r)*rs3 + c4);
    Qs[r][c4+0] = v.x*scale; Qs[r][c4+1] = v.y*scale;
    Qs[r][c4+2] = v.z*scale; Qs[r][c4+3] = v.w*scale;
  }

  float m_i[4], l_i[4], acc_o[4][4];
  #pragma unroll
  for (int i = 0; i < 4; ++i) {
    m_i[i] = -INFINITY; l_i[i] = 0.f;
    #pragma unroll
    for (int j = 0; j < 4; ++j) acc_o[i][j] = 0.f;
  }

  for (int kt = 0; kt <= qt; ++kt) {
    // Stage K and V tiles
    #pragma unroll
    for (int i = 0; i < 4; ++i) {
      int idx = tid + i*256;
      int r = idx >> 4, c4 = (idx & 15) * 4;
      *(float4*)&Ks[r][c4] = *(const float4*)(kbase + (size_t)(kt*64 + r)*rs3 + c4);
      *(float4*)&Vs[r][c4] = *(const float4*)(vbase + (size_t)(kt*64 + r)*rs3 + c4);
    }
    __syncthreads();

    // S = Q * K^T  (4x4 per thread: rows ty*4+i, cols tx*4+j)
    float s[4][4] = {};
    #pragma unroll 4
    for (int kk = 0; kk < 64; ++kk) {
      float a[4], bb[4];
      #pragma unroll
      for (int i = 0; i < 4; ++i) a[i]  = Qs[ty*4+i][kk];
      #pragma unroll
      for (int j = 0; j < 4; ++j) bb[j] = Ks[tx*4+j][kk];
      #pragma unroll
      for (int i = 0; i < 4; ++i)
        #pragma unroll
        for (int j = 0; j < 4; ++j)
          s[i][j] += a[i]*bb[j];
    }
    // causal mask on the diagonal tile
    if (kt == qt) {
      #pragma unroll
      for (int i = 0; i < 4; ++i)
        #pragma unroll
        for (int j = 0; j < 4; ++j)
          if (tx*4+j > ty*4+i) s[i][j] = -INFINITY;
    }

    // online softmax update (per q-row, across the 16 lanes sharing ty)
    float alpha[4];
    #pragma unroll
    for (int i = 0; i < 4; ++i) {
      float rm = fmaxf(fmaxf(s[i][0], s[i][1]), fmaxf(s[i][2], s[i][3]));
      #pragma unroll
      for (int o = 1; o < 16; o <<= 1) rm = fmaxf(rm, __shfl_xor(rm, o, 16));
      float mn = fmaxf(m_i[i], rm);
      alpha[i] = __expf(m_i[i] - mn);
      float rsum = 0.f;
      #pragma unroll
      for (int j = 0; j < 4; ++j) { s[i][j] = __expf(s[i][j] - mn); rsum += s[i][j]; }
      #pragma unroll
      for (int o = 1; o < 16; o <<= 1) rsum += __shfl_xor(rsum, o, 16);
      l_i[i] = l_i[i]*alpha[i] + rsum;
      m_i[i] = mn;
    }

    // P -> LDS (reuse Ks), layout P[qrow][kcol]
    __syncthreads();
    #pragma unroll
    for (int i = 0; i < 4; ++i)
      #pragma unroll
      for (int j = 0; j < 4; ++j)
        Ks[ty*4+i][tx*4+j] = s[i][j];
    __syncthreads();

    // O = O*alpha + P*V   (rows q = ty*4+i, cols d = tx*4+j)
    #pragma unroll
    for (int i = 0; i < 4; ++i)
      #pragma unroll
      for (int j = 0; j < 4; ++j)
        acc_o[i][j] *= alpha[i];
    #pragma unroll 4
    for (int kd = 0; kd < 64; ++kd) {
      float a[4], bb[4];
      #pragma unroll
      for (int i = 0; i < 4; ++i) a[i]  = Ks[ty*4+i][kd];
      #pragma unroll
      for (int j = 0; j < 4; ++j) bb[j] = Vs[kd][tx*4+j];
      #pragma unroll
      for (int i = 0; i < 4; ++i)
        #pragma unroll
        for (int j = 0; j < 4; ++j)
          acc_o[i][j] += a[i]*bb[j];
    }
    __syncthreads();
  }

  // write O / l
  #pragma unroll
  for (int i = 0; i < 4; ++i) {
    float inv = 1.f / l_i[i];
    int qrow = qt*64 + ty*4 + i;
    #pragma unroll
    for (int j = 0; j < 4; ++j)
      out[((size_t)(b*SEQ + qrow))*D_MODEL + h*D_HEAD + tx*4 + j] = acc_o[i][j]*inv;
  }
}

extern "C" void kernel_launch(void* const* d_in, const int* in_sizes, int n_in,
                              void* d_out, int out_size, void* d_ws, size_t ws_size,
                              hipStream_t stream) {
  const float* x      = (const float*)d_in[0];
  const float* ln1_w  = (const float*)d_in[1];
  const float* ln1_b  = (const float*)d_in[2];
  const float* ln2_w  = (const float*)d_in[3];
  const float* ln2_b  = (const float*)d_in[4];
  const float* qkv_w  = (const float*)d_in[5];
  const float* o_w    = (const float*)d_in[6];
  const float* ffn_w1 = (const float*)d_in[7];
  const float* ffn_b1 = (const float*)d_in[8];
  const float* ffn_w2 = (const float*)d_in[9];
  const float* ffn_b2 = (const float*)d_in[10];
  float* out = (float*)d_out;
  float* ws  = (float*)d_ws;

  const size_t MD = (size_t)M_TOT * D_MODEL;      // 4M floats
  float* h    = ws;                               // [0, 4M)   ln1 out, later ln2 out
  float* attn = ws + MD;                          // [4M, 8M)
  float* x1   = ws + 2*MD;                        // [8M, 12M)
  float* qkv  = ws + 3*MD;                        // [12M, 24M) dead after attention
  float* ff   = ws + 3*MD;                        // [12M, 28M) reuses qkv region

  // 1. h = LN1(x)
  ln_kernel<<<M_TOT, 256, 0, stream>>>(x, ln1_w, ln1_b, h);
  // 2. qkv = h @ qkv_w.T        (4096 x 3072 x 1024)
  gemm_bt<0><<<dim3(3*D_MODEL/64, M_TOT/64), 256, 0, stream>>>(
      h, qkv_w, qkv, nullptr, nullptr, M_TOT, 3*D_MODEL, D_MODEL);
  // 3. attn = causal MHA(qkv), flash-style tiles
  attn_tile_kernel<<<dim3(SEQ/64, N_HEADS, BATCH), 256, 0, stream>>>(qkv, attn);
  // 4. x1 = x + attn @ o_w.T    (4096 x 1024 x 1024)
  gemm_bt<2><<<dim3(D_MODEL/64, M_TOT/64), 256, 0, stream>>>(
      attn, o_w, x1, nullptr, x, M_TOT, D_MODEL, D_MODEL);
  // 5. h = LN2(x1)
  ln_kernel<<<M_TOT, 256, 0, stream>>>(x1, ln2_w, ln2_b, h);
  // 6. ff = gelu(h @ ffn_w1.T + b1)   (4096 x 4096 x 1024)
  gemm_bt<1><<<dim3(FFN_DIM/64, M_TOT/64), 256, 0, stream>>>(
      h, ffn_w1, ff, ffn_b1, nullptr, M_TOT, FFN_DIM, D_MODEL);
  // 7. out = x1 + ff @ ffn_w2.T + b2  (4096 x 1024 x 4096)
  gemm_bt<3><<<dim3(D_MODEL/64, M_TOT/64), 256, 0, stream>>>(
      ff, ffn_w2, out, ffn_b2, x1, M_TOT, D_MODEL, FFN_DIM);
}

// Round 3
// 966.686 us; speedup vs baseline: 5.8867x; 2.8463x over previous
//
#include <hip/hip_runtime.h>
#include <math.h>

#define D_MODEL 1024
#define N_HEADS 16
#define D_HEAD  64
#define SEQ     2048
#define BATCH   2
#define M_TOT   (BATCH*SEQ)   // 4096
#define FFN_DIM 4096

typedef __attribute__((ext_vector_type(8))) short bf16x8;   // 8 bf16 = 4 VGPRs
typedef __attribute__((ext_vector_type(4))) float f32x4;

__device__ __forceinline__ unsigned short f2bf(float f) {
  unsigned int u = __float_as_uint(f);
  return (unsigned short)((u + 0x7fffu + ((u >> 16) & 1u)) >> 16);  // RNE
}

__device__ __forceinline__ void async_ld16(void* lds, const void* g) {
  __builtin_amdgcn_global_load_lds(
      (const __attribute__((address_space(1))) unsigned int*)g,
      (__attribute__((address_space(3))) unsigned int*)lds, 16, 0, 0);
}

__device__ __forceinline__ float gelu_exact(float x) {
  return 0.5f * x * (1.f + erff(x * 0.70710678118654752f));
}

// ---------------- fp32 -> bf16 convert (weights) --------------------------------
__global__ __launch_bounds__(256) void cvt_bf16(const float* __restrict__ in,
    unsigned short* __restrict__ out, int n) {
  int i = (blockIdx.x * 256 + threadIdx.x) * 4;
  if (i >= n) return;
  float4 v = *(const float4*)(in + i);
  out[i+0] = f2bf(v.x); out[i+1] = f2bf(v.y);
  out[i+2] = f2bf(v.z); out[i+3] = f2bf(v.w);
}

// ---------------- LayerNorm: one block (256 thr) per row of 1024, bf16 out ------
__global__ __launch_bounds__(256) void ln_kernel(const float* __restrict__ x,
    const float* __restrict__ w, const float* __restrict__ b,
    unsigned short* __restrict__ out) {
  int row = blockIdx.x;
  const float* xr = x + (size_t)row * D_MODEL;
  unsigned short* outr = out + (size_t)row * D_MODEL;
  float v[4];
  float s = 0.f;
  #pragma unroll
  for (int i = 0; i < 4; ++i) { v[i] = xr[threadIdx.x + i*256]; s += v[i]; }
  __shared__ float red[4];
  #pragma unroll
  for (int o = 32; o > 0; o >>= 1) s += __shfl_down(s, o, 64);
  int wave = threadIdx.x >> 6;
  if ((threadIdx.x & 63) == 0) red[wave] = s;
  __syncthreads();
  float mean = (red[0]+red[1]+red[2]+red[3]) * (1.f/D_MODEL);
  __syncthreads();
  float s2 = 0.f;
  #pragma unroll
  for (int i = 0; i < 4; ++i) { float d = v[i]-mean; s2 += d*d; }
  #pragma unroll
  for (int o = 32; o > 0; o >>= 1) s2 += __shfl_down(s2, o, 64);
  if ((threadIdx.x & 63) == 0) red[wave] = s2;
  __syncthreads();
  float var = (red[0]+red[1]+red[2]+red[3]) * (1.f/D_MODEL);
  float rs = rsqrtf(var + 1e-5f);
  #pragma unroll
  for (int i = 0; i < 4; ++i) {
    int c = threadIdx.x + i*256;
    outr[c] = f2bf((v[i]-mean)*rs*w[c] + b[c]);
  }
}

// ---------------- MFMA GEMM: C[m,n] = sum_k A[m,k]*Bt[n,k] (+ epilogue) ---------
// m97 structure: 128x128 tile, BK=32, global_load_lds(16B) staging,
// v_mfma_f32_16x16x32_bf16, 4 waves each owning a 64x64 sub-tile (4x4 frags).
// EPI: 0 = plain, 1 = gelu(x+bias), 2 = +res, 3 = +bias+res.  OBF: bf16 output.
template<int EPI, bool OBF>
__global__ __launch_bounds__(256) void gemm_mfma(
    const unsigned short* __restrict__ A, const unsigned short* __restrict__ Bt,
    float* __restrict__ Cf, unsigned short* __restrict__ Cb,
    const float* __restrict__ bias, const float* __restrict__ res,
    int M, int N, int K) {
  __shared__ unsigned short As[128*32];   // 8 KB, row-major [m][k], no padding
  __shared__ unsigned short Bs[128*32];   // (global_load_lds needs contiguity)
  int tid = threadIdx.x;
  int w = tid >> 6, l = tid & 63;
  int bm = blockIdx.y * 128, bn = blockIdx.x * 128;
  int wm = (w >> 1) * 64, wn = (w & 1) * 64;

  f32x4 acc[4][4];
  #pragma unroll
  for (int i = 0; i < 4; ++i)
    #pragma unroll
    for (int j = 0; j < 4; ++j)
      acc[i][j] = (f32x4){0.f, 0.f, 0.f, 0.f};

  // staging: 8 KB tile = 8 wave-calls of 64 lanes x 16 B; wave w does calls 2w,2w+1
  int f0 = (w*2+0)*512 + l*8;            // flat bf16 index this lane fills, call 0
  int f1 = (w*2+1)*512 + l*8;
  const unsigned short* a0 = A  + (size_t)(bm + (f0 >> 5))*K + (f0 & 31);
  const unsigned short* a1 = A  + (size_t)(bm + (f1 >> 5))*K + (f1 & 31);
  const unsigned short* b0 = Bt + (size_t)(bn + (f0 >> 5))*K + (f0 & 31);
  const unsigned short* b1 = Bt + (size_t)(bn + (f1 >> 5))*K + (f1 & 31);
  unsigned short* la0 = &As[(w*2+0)*512];
  unsigned short* la1 = &As[(w*2+1)*512];
  unsigned short* lb0 = &Bs[(w*2+0)*512];
  unsigned short* lb1 = &Bs[(w*2+1)*512];

  // fragment read offsets (A: m = wm+i*16+(l&15), k = (l>>4)*8)
  int aoff = (wm + (l & 15))*32 + (l >> 4)*8;
  int boff = (wn + (l & 15))*32 + (l >> 4)*8;

  for (int k0 = 0; k0 < K; k0 += 32) {
    async_ld16(la0, a0 + k0);
    async_ld16(la1, a1 + k0);
    async_ld16(lb0, b0 + k0);
    async_ld16(lb1, b1 + k0);
    __syncthreads();               // vmcnt(0) drain + barrier
    bf16x8 af[4], bfr[4];
    #pragma unroll
    for (int i = 0; i < 4; ++i) af[i]  = *(const bf16x8*)&As[aoff + i*512];
    #pragma unroll
    for (int j = 0; j < 4; ++j) bfr[j] = *(const bf16x8*)&Bs[boff + j*512];
    #pragma unroll
    for (int i = 0; i < 4; ++i)
      #pragma unroll
      for (int j = 0; j < 4; ++j)
        acc[i][j] = __builtin_amdgcn_mfma_f32_16x16x32_bf16(af[i], bfr[j], acc[i][j], 0, 0, 0);
    __syncthreads();               // protect LDS from next-iter staging
  }

  // epilogue: C/D layout col = lane&15, row = (lane>>4)*4 + reg  [m89 verified]
  #pragma unroll
  for (int i = 0; i < 4; ++i) {
    #pragma unroll
    for (int j = 0; j < 4; ++j) {
      int col = bn + wn + j*16 + (l & 15);
      #pragma unroll
      for (int r = 0; r < 4; ++r) {
        int row = bm + wm + i*16 + (l >> 4)*4 + r;
        float v = acc[i][j][r];
        if (EPI == 1) v = gelu_exact(v + bias[col]);
        if (EPI == 2) v += res[(size_t)row*N + col];
        if (EPI == 3) v += bias[col] + res[(size_t)row*N + col];
        if (OBF) Cb[(size_t)row*N + col] = f2bf(v);
        else     Cf[(size_t)row*N + col] = v;
      }
    }
  }
}

// ---------------- Flash-style causal attention (fp32 in, bf16 out) --------------
__global__ __launch_bounds__(256) void attn_tile_kernel(
    const float* __restrict__ qkv, unsigned short* __restrict__ out) {
  __shared__ float Qs[64][68];
  __shared__ float Ks[64][68];   // reused as P after S is computed
  __shared__ float Vs[64][68];

  int qt = blockIdx.x;
  int h  = blockIdx.y;
  int b  = blockIdx.z;
  int tid = threadIdx.x;
  int tx = tid & 15, ty = tid >> 4;

  const size_t rs3 = 3*D_MODEL;
  const float* qbase = qkv + (size_t)b*SEQ*rs3 +             h*D_HEAD;
  const float* kbase = qkv + (size_t)b*SEQ*rs3 + D_MODEL   + h*D_HEAD;
  const float* vbase = qkv + (size_t)b*SEQ*rs3 + 2*D_MODEL + h*D_HEAD;

  const float scale = 0.125f;
  #pragma unroll
  for (int i = 0; i < 4; ++i) {
    int idx = tid + i*256;
    int r = idx >> 4, c4 = (idx & 15) * 4;
    float4 v = *(const float4*)(qbase + (size_t)(qt*64 + r)*rs3 + c4);
    Qs[r][c4+0] = v.x*scale; Qs[r][c4+1] = v.y*scale;
    Qs[r][c4+2] = v.z*scale; Qs[r][c4+3] = v.w*scale;
  }

  float m_i[4], l_i[4], acc_o[4][4];
  #pragma unroll
  for (int i = 0; i < 4; ++i) {
    m_i[i] = -INFINITY; l_i[i] = 0.f;
    #pragma unroll
    for (int j = 0; j < 4; ++j) acc_o[i][j] = 0.f;
  }

  for (int kt = 0; kt <= qt; ++kt) {
    #pragma unroll
    for (int i = 0; i < 4; ++i) {
      int idx = tid + i*256;
      int r = idx >> 4, c4 = (idx & 15) * 4;
      *(float4*)&Ks[r][c4] = *(const float4*)(kbase + (size_t)(kt*64 + r)*rs3 + c4);
      *(float4*)&Vs[r][c4] = *(const float4*)(vbase + (size_t)(kt*64 + r)*rs3 + c4);
    }
    __syncthreads();

    float s[4][4] = {};
    #pragma unroll 4
    for (int kk = 0; kk < 64; ++kk) {
      float a[4], bb[4];
      #pragma unroll
      for (int i = 0; i < 4; ++i) a[i]  = Qs[ty*4+i][kk];
      #pragma unroll
      for (int j = 0; j < 4; ++j) bb[j] = Ks[tx*4+j][kk];
      #pragma unroll
      for (int i = 0; i < 4; ++i)
        #pragma unroll
        for (int j = 0; j < 4; ++j)
          s[i][j] += a[i]*bb[j];
    }
    if (kt == qt) {
      #pragma unroll
      for (int i = 0; i < 4; ++i)
        #pragma unroll
        for (int j = 0; j < 4; ++j)
          if (tx*4+j > ty*4+i) s[i][j] = -INFINITY;
    }

    float alpha[4];
    #pragma unroll
    for (int i = 0; i < 4; ++i) {
      float rm = fmaxf(fmaxf(s[i][0], s[i][1]), fmaxf(s[i][2], s[i][3]));
      #pragma unroll
      for (int o = 1; o < 16; o <<= 1) rm = fmaxf(rm, __shfl_xor(rm, o, 16));
      float mn = fmaxf(m_i[i], rm);
      alpha[i] = __expf(m_i[i] - mn);
      float rsum = 0.f;
      #pragma unroll
      for (int j = 0; j < 4; ++j) { s[i][j] = __expf(s[i][j] - mn); rsum += s[i][j]; }
      #pragma unroll
      for (int o = 1; o < 16; o <<= 1) rsum += __shfl_xor(rsum, o, 16);
      l_i[i] = l_i[i]*alpha[i] + rsum;
      m_i[i] = mn;
    }

    __syncthreads();
    #pragma unroll
    for (int i = 0; i < 4; ++i)
      #pragma unroll
      for (int j = 0; j < 4; ++j)
        Ks[ty*4+i][tx*4+j] = s[i][j];
    __syncthreads();

    #pragma unroll
    for (int i = 0; i < 4; ++i)
      #pragma unroll
      for (int j = 0; j < 4; ++j)
        acc_o[i][j] *= alpha[i];
    #pragma unroll 4
    for (int kd = 0; kd < 64; ++kd) {
      float a[4], bb[4];
      #pragma unroll
      for (int i = 0; i < 4; ++i) a[i]  = Ks[ty*4+i][kd];
      #pragma unroll
      for (int j = 0; j < 4; ++j) bb[j] = Vs[kd][tx*4+j];
      #pragma unroll
      for (int i = 0; i < 4; ++i)
        #pragma unroll
        for (int j = 0; j < 4; ++j)
          acc_o[i][j] += a[i]*bb[j];
    }
    __syncthreads();
  }

  #pragma unroll
  for (int i = 0; i < 4; ++i) {
    float inv = 1.f / l_i[i];
    int qrow = qt*64 + ty*4 + i;
    #pragma unroll
    for (int j = 0; j < 4; ++j)
      out[((size_t)(b*SEQ + qrow))*D_MODEL + h*D_HEAD + tx*4 + j] = f2bf(acc_o[i][j]*inv);
  }
}

extern "C" void kernel_launch(void* const* d_in, const int* in_sizes, int n_in,
                              void* d_out, int out_size, void* d_ws, size_t ws_size,
                              hipStream_t stream) {
  const float* x      = (const float*)d_in[0];
  const float* ln1_w  = (const float*)d_in[1];
  const float* ln1_b  = (const float*)d_in[2];
  const float* ln2_w  = (const float*)d_in[3];
  const float* ln2_b  = (const float*)d_in[4];
  const float* qkv_w  = (const float*)d_in[5];
  const float* o_w    = (const float*)d_in[6];
  const float* ffn_w1 = (const float*)d_in[7];
  const float* ffn_b1 = (const float*)d_in[8];
  const float* ffn_w2 = (const float*)d_in[9];
  const float* ffn_b2 = (const float*)d_in[10];
  float* out = (float*)d_out;
  float* ws  = (float*)d_ws;

  const size_t MEG = 1024*1024;
  // bf16 weights: 12M ushort = 6M floats at [0, 6M)
  unsigned short* wqkv = (unsigned short*)ws;            // 3M
  unsigned short* wo   = wqkv + 3*MEG;                   // 1M
  unsigned short* w1   = wo   + 1*MEG;                   // 4M
  unsigned short* w2   = w1   + 4*MEG;                   // 4M
  unsigned short* hbf    = (unsigned short*)(ws + 6*MEG);  // [6M,8M)  4M ushort (h / h2)
  unsigned short* attnbf = (unsigned short*)(ws + 8*MEG);  // [8M,10M) 4M ushort
  float* x1  = ws + 10*MEG;                                // [10M,14M)
  float* qkv = ws + 14*MEG;                                // [14M,26M) fp32, dead after attn
  unsigned short* ffbf = (unsigned short*)qkv;             // reuses qkv region (8M floats)

  // 0. weights -> bf16
  cvt_bf16<<<3*MEG/1024, 256, 0, stream>>>(qkv_w, wqkv, 3*MEG);
  cvt_bf16<<<1*MEG/1024, 256, 0, stream>>>(o_w,   wo,   1*MEG);
  cvt_bf16<<<4*MEG/1024, 256, 0, stream>>>(ffn_w1, w1,  4*MEG);
  cvt_bf16<<<4*MEG/1024, 256, 0, stream>>>(ffn_w2, w2,  4*MEG);
  // 1. h = LN1(x) -> bf16
  ln_kernel<<<M_TOT, 256, 0, stream>>>(x, ln1_w, ln1_b, hbf);
  // 2. qkv = h @ qkv_w.T  (4096 x 3072 x 1024) -> fp32
  gemm_mfma<0,false><<<dim3(3*D_MODEL/128, M_TOT/128), 256, 0, stream>>>(
      hbf, wqkv, qkv, nullptr, nullptr, nullptr, M_TOT, 3*D_MODEL, D_MODEL);
  // 3. attn = causal MHA(qkv) -> bf16
  attn_tile_kernel<<<dim3(SEQ/64, N_HEADS, BATCH), 256, 0, stream>>>(qkv, attnbf);
  // 4. x1 = x + attn @ o_w.T  (4096 x 1024 x 1024) -> fp32
  gemm_mfma<2,false><<<dim3(D_MODEL/128, M_TOT/128), 256, 0, stream>>>(
      attnbf, wo, x1, nullptr, nullptr, x, M_TOT, D_MODEL, D_MODEL);
  // 5. h2 = LN2(x1) -> bf16
  ln_kernel<<<M_TOT, 256, 0, stream>>>(x1, ln2_w, ln2_b, hbf);
  // 6. ff = gelu(h2 @ ffn_w1.T + b1)  (4096 x 4096 x 1024) -> bf16
  gemm_mfma<1,true><<<dim3(FFN_DIM/128, M_TOT/128), 256, 0, stream>>>(
      hbf, w1, nullptr, ffbf, ffn_b1, nullptr, M_TOT, FFN_DIM, D_MODEL);
  // 7. out = x1 + ff @ ffn_w2.T + b2  (4096 x 1024 x 4096) -> fp32
  gemm_mfma<3,false><<<dim3(D_MODEL/128, M_TOT/128), 256, 0, stream>>>(
      ffbf, w2, out, nullptr, ffn_b2, x1, M_TOT, D_MODEL, FFN_DIM);
}

// Round 4
// 520.840 us; speedup vs baseline: 10.9258x; 1.8560x over previous
//
#include <hip/hip_runtime.h>
#include <math.h>

#define D_MODEL 1024
#define N_HEADS 16
#define D_HEAD  64
#define SEQ     2048
#define BATCH   2
#define M_TOT   (BATCH*SEQ)   // 4096
#define FFN_DIM 4096

typedef __attribute__((ext_vector_type(8))) short bf16x8;   // 8 bf16 = 4 VGPRs
typedef __attribute__((ext_vector_type(4))) float f32x4;
typedef __attribute__((ext_vector_type(8))) unsigned short u16x8;

__device__ __forceinline__ unsigned short f2bf(float f) {
  unsigned int u = __float_as_uint(f);
  return (unsigned short)((u + 0x7fffu + ((u >> 16) & 1u)) >> 16);  // RNE
}
__device__ __forceinline__ float bf2f(unsigned short s) {
  return __uint_as_float(((unsigned int)s) << 16);
}

__device__ __forceinline__ void async_ld16(void* lds, const void* g) {
  __builtin_amdgcn_global_load_lds(
      (const __attribute__((address_space(1))) unsigned int*)g,
      (__attribute__((address_space(3))) unsigned int*)lds, 16, 0, 0);
}

__device__ __forceinline__ float gelu_exact(float x) {
  return 0.5f * x * (1.f + erff(x * 0.70710678118654752f));
}

// ---------------- fp32 -> bf16 convert (weights) --------------------------------
__global__ __launch_bounds__(256) void cvt_bf16(const float* __restrict__ in,
    unsigned short* __restrict__ out, int n) {
  int i = (blockIdx.x * 256 + threadIdx.x) * 4;
  if (i >= n) return;
  float4 v = *(const float4*)(in + i);
  out[i+0] = f2bf(v.x); out[i+1] = f2bf(v.y);
  out[i+2] = f2bf(v.z); out[i+3] = f2bf(v.w);
}

// ---------------- LayerNorm: one block (256 thr) per row of 1024, bf16 out ------
__global__ __launch_bounds__(256) void ln_kernel(const float* __restrict__ x,
    const float* __restrict__ w, const float* __restrict__ b,
    unsigned short* __restrict__ out) {
  int row = blockIdx.x;
  const float* xr = x + (size_t)row * D_MODEL;
  unsigned short* outr = out + (size_t)row * D_MODEL;
  float v[4];
  float s = 0.f;
  #pragma unroll
  for (int i = 0; i < 4; ++i) { v[i] = xr[threadIdx.x + i*256]; s += v[i]; }
  __shared__ float red[4];
  #pragma unroll
  for (int o = 32; o > 0; o >>= 1) s += __shfl_down(s, o, 64);
  int wave = threadIdx.x >> 6;
  if ((threadIdx.x & 63) == 0) red[wave] = s;
  __syncthreads();
  float mean = (red[0]+red[1]+red[2]+red[3]) * (1.f/D_MODEL);
  __syncthreads();
  float s2 = 0.f;
  #pragma unroll
  for (int i = 0; i < 4; ++i) { float d = v[i]-mean; s2 += d*d; }
  #pragma unroll
  for (int o = 32; o > 0; o >>= 1) s2 += __shfl_down(s2, o, 64);
  if ((threadIdx.x & 63) == 0) red[wave] = s2;
  __syncthreads();
  float var = (red[0]+red[1]+red[2]+red[3]) * (1.f/D_MODEL);
  float rs = rsqrtf(var + 1e-5f);
  #pragma unroll
  for (int i = 0; i < 4; ++i) {
    int c = threadIdx.x + i*256;
    outr[c] = f2bf((v[i]-mean)*rs*w[c] + b[c]);
  }
}

// ---------------- MFMA GEMM: C[m,n] = sum_k A[m,k]*Bt[n,k] (+ epilogue) ---------
template<int EPI, bool OBF>
__global__ __launch_bounds__(256) void gemm_mfma(
    const unsigned short* __restrict__ A, const unsigned short* __restrict__ Bt,
    float* __restrict__ Cf, unsigned short* __restrict__ Cb,
    const float* __restrict__ bias, const float* __restrict__ res,
    int M, int N, int K) {
  __shared__ unsigned short As[128*32];   // 8 KB, row-major [m][k], no padding
  __shared__ unsigned short Bs[128*32];
  int tid = threadIdx.x;
  int w = tid >> 6, l = tid & 63;
  int bm = blockIdx.y * 128, bn = blockIdx.x * 128;
  int wm = (w >> 1) * 64, wn = (w & 1) * 64;

  f32x4 acc[4][4];
  #pragma unroll
  for (int i = 0; i < 4; ++i)
    #pragma unroll
    for (int j = 0; j < 4; ++j)
      acc[i][j] = (f32x4){0.f, 0.f, 0.f, 0.f};

  int f0 = (w*2+0)*512 + l*8;
  int f1 = (w*2+1)*512 + l*8;
  const unsigned short* a0 = A  + (size_t)(bm + (f0 >> 5))*K + (f0 & 31);
  const unsigned short* a1 = A  + (size_t)(bm + (f1 >> 5))*K + (f1 & 31);
  const unsigned short* b0 = Bt + (size_t)(bn + (f0 >> 5))*K + (f0 & 31);
  const unsigned short* b1 = Bt + (size_t)(bn + (f1 >> 5))*K + (f1 & 31);
  unsigned short* la0 = &As[(w*2+0)*512];
  unsigned short* la1 = &As[(w*2+1)*512];
  unsigned short* lb0 = &Bs[(w*2+0)*512];
  unsigned short* lb1 = &Bs[(w*2+1)*512];

  int aoff = (wm + (l & 15))*32 + (l >> 4)*8;
  int boff = (wn + (l & 15))*32 + (l >> 4)*8;

  for (int k0 = 0; k0 < K; k0 += 32) {
    async_ld16(la0, a0 + k0);
    async_ld16(la1, a1 + k0);
    async_ld16(lb0, b0 + k0);
    async_ld16(lb1, b1 + k0);
    __syncthreads();
    bf16x8 af[4], bfr[4];
    #pragma unroll
    for (int i = 0; i < 4; ++i) af[i]  = *(const bf16x8*)&As[aoff + i*512];
    #pragma unroll
    for (int j = 0; j < 4; ++j) bfr[j] = *(const bf16x8*)&Bs[boff + j*512];
    #pragma unroll
    for (int i = 0; i < 4; ++i)
      #pragma unroll
      for (int j = 0; j < 4; ++j)
        acc[i][j] = __builtin_amdgcn_mfma_f32_16x16x32_bf16(af[i], bfr[j], acc[i][j], 0, 0, 0);
    __syncthreads();
  }

  #pragma unroll
  for (int i = 0; i < 4; ++i) {
    #pragma unroll
    for (int j = 0; j < 4; ++j) {
      int col = bn + wn + j*16 + (l & 15);
      #pragma unroll
      for (int r = 0; r < 4; ++r) {
        int row = bm + wm + i*16 + (l >> 4)*4 + r;
        float v = acc[i][j][r];
        if (EPI == 1) v = gelu_exact(v + bias[col]);
        if (EPI == 2) v += res[(size_t)row*N + col];
        if (EPI == 3) v += bias[col] + res[(size_t)row*N + col];
        if (OBF) Cb[(size_t)row*N + col] = f2bf(v);
        else     Cf[(size_t)row*N + col] = v;
      }
    }
  }
}

// ---------------- MFMA flash attention (bf16 in, bf16 out) ----------------------
// Block = 4 waves per (64-q-tile, head, batch). Wave w owns q-rows [w*16,w*16+16).
// K LDS [kv][d] (pad 72), V^T LDS [d][kv] (pad 72), per-wave P strip [16][72].
// S = Q K^T and O += P V via mfma_f32_16x16x32_bf16; online softmax on C layout.
#define ATT_PAD 72
__global__ __launch_bounds__(256) void attn_mfma_kernel(
    const unsigned short* __restrict__ qkvb, unsigned short* __restrict__ out) {
  __shared__ unsigned short Ks[64*ATT_PAD];
  __shared__ unsigned short Vt[64*ATT_PAD];
  __shared__ unsigned short Pw[4][16*ATT_PAD];

  int qt = blockIdx.x, h = blockIdx.y, b = blockIdx.z;
  int tid = threadIdx.x;
  int w = tid >> 6, l = tid & 63;
  int lg = l >> 4, lm = l & 15;

  const size_t rs3 = 3*D_MODEL;
  const unsigned short* qb = qkvb + (size_t)(b*SEQ)*rs3 + h*D_HEAD;
  const unsigned short* kb = qb + D_MODEL;
  const unsigned short* vb = qb + 2*D_MODEL;

  // Q A-frags (held in regs for whole block), pre-scaled by 1/8 (exact pow2)
  int qrow = qt*64 + w*16 + lm;
  bf16x8 aq[2];
  #pragma unroll
  for (int s = 0; s < 2; ++s) {
    u16x8 t = *(const u16x8*)(qb + (size_t)qrow*rs3 + s*32 + lg*8);
    bf16x8 r;
    #pragma unroll
    for (int i = 0; i < 8; ++i) r[i] = (short)f2bf(bf2f(t[i]) * 0.125f);
    aq[s] = r;
  }

  float m_i[4], l_i[4];
  f32x4 acc_o[4];
  #pragma unroll
  for (int r = 0; r < 4; ++r) { m_i[r] = -INFINITY; l_i[r] = 0.f; }
  #pragma unroll
  for (int j = 0; j < 4; ++j) acc_o[j] = (f32x4){0.f, 0.f, 0.f, 0.f};

  for (int kt = 0; kt <= qt; ++kt) {
    // stage K tile [64][64] and transposed V tile
    #pragma unroll
    for (int it = 0; it < 2; ++it) {
      int idx = tid + it*256;              // 0..511
      int r = idx >> 3, c8 = (idx & 7)*8;
      u16x8 kv8 = *(const u16x8*)(kb + (size_t)(kt*64 + r)*rs3 + c8);
      *(u16x8*)&Ks[r*ATT_PAD + c8] = kv8;
      u16x8 vv8 = *(const u16x8*)(vb + (size_t)(kt*64 + r)*rs3 + c8);
      #pragma unroll
      for (int i = 0; i < 8; ++i) Vt[(c8+i)*ATT_PAD + r] = vv8[i];
    }
    __syncthreads();

    // S = Q K^T : 4 n-tiles x 2 k-steps
    f32x4 sacc[4];
    #pragma unroll
    for (int j = 0; j < 4; ++j) sacc[j] = (f32x4){0.f, 0.f, 0.f, 0.f};
    #pragma unroll
    for (int s = 0; s < 2; ++s)
      #pragma unroll
      for (int j = 0; j < 4; ++j)
        sacc[j] = __builtin_amdgcn_mfma_f32_16x16x32_bf16(
            aq[s], *(const bf16x8*)&Ks[(j*16+lm)*ATT_PAD + s*32 + lg*8], sacc[j], 0, 0, 0);

    // causal mask on diagonal tile: local q-row = w*16+lg*4+r, kv col = j*16+lm
    if (kt == qt) {
      #pragma unroll
      for (int j = 0; j < 4; ++j)
        #pragma unroll
        for (int r = 0; r < 4; ++r)
          if (j*16 + lm > w*16 + lg*4 + r) sacc[j][r] = -INFINITY;
    }

    // online softmax (per row r; cols spread over j and the 16-lane group)
    float alpha[4];
    #pragma unroll
    for (int r = 0; r < 4; ++r) {
      float rm = fmaxf(fmaxf(sacc[0][r], sacc[1][r]), fmaxf(sacc[2][r], sacc[3][r]));
      #pragma unroll
      for (int o = 1; o < 16; o <<= 1) rm = fmaxf(rm, __shfl_xor(rm, o));
      float mn = fmaxf(m_i[r], rm);
      alpha[r] = __expf(m_i[r] - mn);
      float rsum = 0.f;
      #pragma unroll
      for (int j = 0; j < 4; ++j) {
        float p = __expf(sacc[j][r] - mn);
        sacc[j][r] = p; rsum += p;
      }
      #pragma unroll
      for (int o = 1; o < 16; o <<= 1) rsum += __shfl_xor(rsum, o);
      l_i[r] = l_i[r]*alpha[r] + rsum;
      m_i[r] = mn;
    }

    // P (C layout) -> per-wave LDS strip (A layout), bf16
    unsigned short* pw = &Pw[w][0];
    #pragma unroll
    for (int j = 0; j < 4; ++j)
      #pragma unroll
      for (int r = 0; r < 4; ++r)
        pw[(lg*4 + r)*ATT_PAD + j*16 + lm] = f2bf(sacc[j][r]);

    // O = O*alpha + P V
    #pragma unroll
    for (int j = 0; j < 4; ++j)
      #pragma unroll
      for (int r = 0; r < 4; ++r)
        acc_o[j][r] *= alpha[r];
    #pragma unroll
    for (int s = 0; s < 2; ++s) {
      bf16x8 ap = *(const bf16x8*)&pw[lm*ATT_PAD + s*32 + lg*8];
      #pragma unroll
      for (int j = 0; j < 4; ++j)
        acc_o[j] = __builtin_amdgcn_mfma_f32_16x16x32_bf16(
            ap, *(const bf16x8*)&Vt[(j*16+lm)*ATT_PAD + s*32 + lg*8], acc_o[j], 0, 0, 0);
    }
    __syncthreads();
  }

  #pragma unroll
  for (int r = 0; r < 4; ++r) {
    float inv = 1.f / l_i[r];
    int qr = qt*64 + w*16 + lg*4 + r;
    #pragma unroll
    for (int j = 0; j < 4; ++j)
      out[((size_t)(b*SEQ + qr))*D_MODEL + h*D_HEAD + j*16 + lm] = f2bf(acc_o[j][r]*inv);
  }
}

extern "C" void kernel_launch(void* const* d_in, const int* in_sizes, int n_in,
                              void* d_out, int out_size, void* d_ws, size_t ws_size,
                              hipStream_t stream) {
  const float* x      = (const float*)d_in[0];
  const float* ln1_w  = (const float*)d_in[1];
  const float* ln1_b  = (const float*)d_in[2];
  const float* ln2_w  = (const float*)d_in[3];
  const float* ln2_b  = (const float*)d_in[4];
  const float* qkv_w  = (const float*)d_in[5];
  const float* o_w    = (const float*)d_in[6];
  const float* ffn_w1 = (const float*)d_in[7];
  const float* ffn_b1 = (const float*)d_in[8];
  const float* ffn_w2 = (const float*)d_in[9];
  const float* ffn_b2 = (const float*)d_in[10];
  float* out = (float*)d_out;
  float* ws  = (float*)d_ws;

  const size_t MEG = 1024*1024;
  // bf16 weights: 12M shorts at [0, 6M) floats
  unsigned short* wqkv = (unsigned short*)ws;              // 3M shorts
  unsigned short* wo   = wqkv + 3*MEG;                     // 1M
  unsigned short* w1   = wo   + 1*MEG;                     // 4M
  unsigned short* w2   = w1   + 4*MEG;                     // 4M
  unsigned short* hbf    = (unsigned short*)(ws + 6*MEG);  // [6M,8M)  h / h2
  unsigned short* attnbf = (unsigned short*)(ws + 8*MEG);  // [8M,10M)
  float* x1  = ws + 10*MEG;                                // [10M,14M)
  unsigned short* qkvb = (unsigned short*)(ws + 14*MEG);   // [14M,20M) 12M shorts, dead after attn
  unsigned short* ffbf = (unsigned short*)(ws + 14*MEG);   // [14M,22M) 16M shorts, reuses qkvb

  // 0. weights -> bf16
  cvt_bf16<<<3*MEG/1024, 256, 0, stream>>>(qkv_w, wqkv, 3*MEG);
  cvt_bf16<<<1*MEG/1024, 256, 0, stream>>>(o_w,   wo,   1*MEG);
  cvt_bf16<<<4*MEG/1024, 256, 0, stream>>>(ffn_w1, w1,  4*MEG);
  cvt_bf16<<<4*MEG/1024, 256, 0, stream>>>(ffn_w2, w2,  4*MEG);
  // 1. h = LN1(x) -> bf16
  ln_kernel<<<M_TOT, 256, 0, stream>>>(x, ln1_w, ln1_b, hbf);
  // 2. qkv = h @ qkv_w.T  (4096 x 3072 x 1024) -> bf16
  gemm_mfma<0,true><<<dim3(3*D_MODEL/128, M_TOT/128), 256, 0, stream>>>(
      hbf, wqkv, nullptr, qkvb, nullptr, nullptr, M_TOT, 3*D_MODEL, D_MODEL);
  // 3. attn = causal MHA(qkv) -> bf16, MFMA flash
  attn_mfma_kernel<<<dim3(SEQ/64, N_HEADS, BATCH), 256, 0, stream>>>(qkvb, attnbf);
  // 4. x1 = x + attn @ o_w.T  (4096 x 1024 x 1024) -> fp32
  gemm_mfma<2,false><<<dim3(D_MODEL/128, M_TOT/128), 256, 0, stream>>>(
      attnbf, wo, x1, nullptr, nullptr, x, M_TOT, D_MODEL, D_MODEL);
  // 5. h2 = LN2(x1) -> bf16
  ln_kernel<<<M_TOT, 256, 0, stream>>>(x1, ln2_w, ln2_b, hbf);
  // 6. ff = gelu(h2 @ ffn_w1.T + b1)  (4096 x 4096 x 1024) -> bf16
  gemm_mfma<1,true><<<dim3(FFN_DIM/128, M_TOT/128), 256, 0, stream>>>(
      hbf, w1, nullptr, ffbf, ffn_b1, nullptr, M_TOT, FFN_DIM, D_MODEL);
  // 7. out = x1 + ff @ ffn_w2.T + b2  (4096 x 1024 x 4096) -> fp32
  gemm_mfma<3,false><<<dim3(D_MODEL/128, M_TOT/128), 256, 0, stream>>>(
      ffbf, w2, out, nullptr, ffn_b2, x1, M_TOT, D_MODEL, FFN_DIM);
}

// Round 5
// 433.622 us; speedup vs baseline: 13.1234x; 1.2011x over previous
//
#include <hip/hip_runtime.h>
#include <math.h>

#define D_MODEL 1024
#define N_HEADS 16
#define D_HEAD  64
#define SEQ     2048
#define BATCH   2
#define M_TOT   (BATCH*SEQ)   // 4096
#define FFN_DIM 4096

typedef __attribute__((ext_vector_type(8))) short bf16x8;   // 8 bf16 = 4 VGPRs
typedef __attribute__((ext_vector_type(4))) float f32x4;
typedef __attribute__((ext_vector_type(8))) unsigned short u16x8;

__device__ __forceinline__ unsigned short f2bf(float f) {
  unsigned int u = __float_as_uint(f);
  return (unsigned short)((u + 0x7fffu + ((u >> 16) & 1u)) >> 16);  // RNE
}
__device__ __forceinline__ float bf2f(unsigned short s) {
  return __uint_as_float(((unsigned int)s) << 16);
}

__device__ __forceinline__ void async_ld16(void* lds, const void* g) {
  __builtin_amdgcn_global_load_lds(
      (const __attribute__((address_space(1))) unsigned int*)g,
      (__attribute__((address_space(3))) unsigned int*)lds, 16, 0, 0);
}

__device__ __forceinline__ float gelu_exact(float x) {
  return 0.5f * x * (1.f + erff(x * 0.70710678118654752f));
}

// ---------------- fp32 -> bf16 convert, all 4 weight tensors in one launch ------
__global__ __launch_bounds__(256) void cvt_all(const float* __restrict__ qkv_w,
    const float* __restrict__ o_w, const float* __restrict__ w1,
    const float* __restrict__ w2, unsigned short* __restrict__ dst) {
  const long MEGc = 1024*1024;
  long i = (long)(blockIdx.x*256 + threadIdx.x)*4;   // [0, 12M)
  const float* src; long off;
  if (i < 3*MEGc)      { src = qkv_w; off = i; }
  else if (i < 4*MEGc) { src = o_w;  off = i - 3*MEGc; }
  else if (i < 8*MEGc) { src = w1;   off = i - 4*MEGc; }
  else                 { src = w2;   off = i - 8*MEGc; }
  float4 v = *(const float4*)(src + off);
  ushort4 o = { f2bf(v.x), f2bf(v.y), f2bf(v.z), f2bf(v.w) };
  *(ushort4*)(dst + i) = o;
}

// ---------------- LayerNorm: one block (256 thr) per row of 1024, bf16 out ------
__global__ __launch_bounds__(256) void ln_kernel(const float* __restrict__ x,
    const float* __restrict__ w, const float* __restrict__ b,
    unsigned short* __restrict__ out) {
  int row = blockIdx.x;
  const float* xr = x + (size_t)row * D_MODEL;
  int c = threadIdx.x * 4;
  float4 v = *(const float4*)(xr + c);
  float s = v.x + v.y + v.z + v.w;
  __shared__ float red[4];
  #pragma unroll
  for (int o = 32; o > 0; o >>= 1) s += __shfl_down(s, o, 64);
  int wave = threadIdx.x >> 6;
  if ((threadIdx.x & 63) == 0) red[wave] = s;
  __syncthreads();
  float mean = (red[0]+red[1]+red[2]+red[3]) * (1.f/D_MODEL);
  __syncthreads();
  float d0 = v.x-mean, d1 = v.y-mean, d2 = v.z-mean, d3 = v.w-mean;
  float s2 = d0*d0 + d1*d1 + d2*d2 + d3*d3;
  #pragma unroll
  for (int o = 32; o > 0; o >>= 1) s2 += __shfl_down(s2, o, 64);
  if ((threadIdx.x & 63) == 0) red[wave] = s2;
  __syncthreads();
  float var = (red[0]+red[1]+red[2]+red[3]) * (1.f/D_MODEL);
  float rs = rsqrtf(var + 1e-5f);
  float4 wv = *(const float4*)(w + c);
  float4 bv = *(const float4*)(b + c);
  ushort4 o = { f2bf(d0*rs*wv.x + bv.x), f2bf(d1*rs*wv.y + bv.y),
                f2bf(d2*rs*wv.z + bv.z), f2bf(d3*rs*wv.w + bv.w) };
  *(ushort4*)(out + (size_t)row*D_MODEL + c) = o;
}

// ---------------- MFMA GEMM: C[m,n] = sum_k A[m,k]*Bt[n,k] (+ epilogue) ---------
template<int EPI, bool OBF>
__global__ __launch_bounds__(256) void gemm_mfma(
    const unsigned short* __restrict__ A, const unsigned short* __restrict__ Bt,
    float* __restrict__ Cf, unsigned short* __restrict__ Cb,
    const float* __restrict__ bias, const float* __restrict__ res,
    int M, int N, int K) {
  __shared__ unsigned short As[128*32];   // 8 KB, row-major [m][k], no padding
  __shared__ unsigned short Bs[128*32];
  int tid = threadIdx.x;
  int w = tid >> 6, l = tid & 63;
  int bm = blockIdx.y * 128, bn = blockIdx.x * 128;
  int wm = (w >> 1) * 64, wn = (w & 1) * 64;

  f32x4 acc[4][4];
  #pragma unroll
  for (int i = 0; i < 4; ++i)
    #pragma unroll
    for (int j = 0; j < 4; ++j)
      acc[i][j] = (f32x4){0.f, 0.f, 0.f, 0.f};

  int f0 = (w*2+0)*512 + l*8;
  int f1 = (w*2+1)*512 + l*8;
  const unsigned short* a0 = A  + (size_t)(bm + (f0 >> 5))*K + (f0 & 31);
  const unsigned short* a1 = A  + (size_t)(bm + (f1 >> 5))*K + (f1 & 31);
  const unsigned short* b0 = Bt + (size_t)(bn + (f0 >> 5))*K + (f0 & 31);
  const unsigned short* b1 = Bt + (size_t)(bn + (f1 >> 5))*K + (f1 & 31);
  unsigned short* la0 = &As[(w*2+0)*512];
  unsigned short* la1 = &As[(w*2+1)*512];
  unsigned short* lb0 = &Bs[(w*2+0)*512];
  unsigned short* lb1 = &Bs[(w*2+1)*512];

  int aoff = (wm + (l & 15))*32 + (l >> 4)*8;
  int boff = (wn + (l & 15))*32 + (l >> 4)*8;

  for (int k0 = 0; k0 < K; k0 += 32) {
    async_ld16(la0, a0 + k0);
    async_ld16(la1, a1 + k0);
    async_ld16(lb0, b0 + k0);
    async_ld16(lb1, b1 + k0);
    __syncthreads();
    bf16x8 af[4], bfr[4];
    #pragma unroll
    for (int i = 0; i < 4; ++i) af[i]  = *(const bf16x8*)&As[aoff + i*512];
    #pragma unroll
    for (int j = 0; j < 4; ++j) bfr[j] = *(const bf16x8*)&Bs[boff + j*512];
    #pragma unroll
    for (int i = 0; i < 4; ++i)
      #pragma unroll
      for (int j = 0; j < 4; ++j)
        acc[i][j] = __builtin_amdgcn_mfma_f32_16x16x32_bf16(af[i], bfr[j], acc[i][j], 0, 0, 0);
    __syncthreads();
  }

  #pragma unroll
  for (int i = 0; i < 4; ++i) {
    #pragma unroll
    for (int j = 0; j < 4; ++j) {
      int col = bn + wn + j*16 + (l & 15);
      #pragma unroll
      for (int r = 0; r < 4; ++r) {
        int row = bm + wm + i*16 + (l >> 4)*4 + r;
        float v = acc[i][j][r];
        if (EPI == 1) v = gelu_exact(v + bias[col]);
        if (EPI == 2) v += res[(size_t)row*N + col];
        if (EPI == 3) v += bias[col] + res[(size_t)row*N + col];
        if (OBF) Cb[(size_t)row*N + col] = f2bf(v);
        else     Cf[(size_t)row*N + col] = v;
      }
    }
  }
}

// ---------------- V transpose: qkv V-part -> vT[b][h][d][seq] -------------------
__global__ __launch_bounds__(256) void vtrans_kernel(
    const unsigned short* __restrict__ qkvb, unsigned short* __restrict__ vT) {
  __shared__ unsigned short T[64*72];
  int nt = blockIdx.x, h = blockIdx.y, b = blockIdx.z;
  int tid = threadIdx.x;
  const unsigned short* vb = qkvb + (size_t)(b*SEQ)*(3*D_MODEL) + 2*D_MODEL + h*D_HEAD;
  #pragma unroll
  for (int it = 0; it < 2; ++it) {
    int idx = tid + it*256;
    int r = idx >> 3, c8 = (idx & 7)*8;        // r = seq-local, c8 = d
    *(u16x8*)&T[r*72 + c8] = *(const u16x8*)(vb + (size_t)(nt*64 + r)*(3*D_MODEL) + c8);
  }
  __syncthreads();
  unsigned short* vto = vT + ((size_t)(b*N_HEADS + h)*D_HEAD)*SEQ + nt*64;
  #pragma unroll
  for (int it = 0; it < 2; ++it) {
    int idx = tid + it*256;
    int d = idx >> 3, s8 = (idx & 7)*8;        // d row, s8 = seq-local
    u16x8 o;
    #pragma unroll
    for (int i = 0; i < 8; ++i) o[i] = T[(s8+i)*72 + d];
    *(u16x8*)(vto + (size_t)d*SEQ + s8) = o;
  }
}

// ---------------- MFMA flash attention, paired q-tiles for load balance ---------
// Block = 4 waves per (pair, head, batch); pair pr handles q-tiles qtH=31-pr and
// qtL=pr (33 compute-steps per block, perfectly balanced). K [kv][d] and
// V^T [d][kv] staged once per kt, shared by both q-tiles.
#define ATT_PAD 72
__device__ __forceinline__ void attn_step(
    const bf16x8* aq, float* m_i, float* l_i, f32x4* acc_o,
    const unsigned short* __restrict__ Ks, const unsigned short* __restrict__ Vt,
    unsigned short* __restrict__ pw, int lg, int lm, int qoff, bool diag) {
  f32x4 sacc[4];
  #pragma unroll
  for (int j = 0; j < 4; ++j) sacc[j] = (f32x4){0.f, 0.f, 0.f, 0.f};
  #pragma unroll
  for (int s = 0; s < 2; ++s)
    #pragma unroll
    for (int j = 0; j < 4; ++j)
      sacc[j] = __builtin_amdgcn_mfma_f32_16x16x32_bf16(
          aq[s], *(const bf16x8*)&Ks[(j*16+lm)*ATT_PAD + s*32 + lg*8], sacc[j], 0, 0, 0);
  if (diag) {
    #pragma unroll
    for (int j = 0; j < 4; ++j)
      #pragma unroll
      for (int r = 0; r < 4; ++r)
        if (j*16 + lm > qoff + lg*4 + r) sacc[j][r] = -INFINITY;
  }
  float alpha[4];
  #pragma unroll
  for (int r = 0; r < 4; ++r) {
    float rm = fmaxf(fmaxf(sacc[0][r], sacc[1][r]), fmaxf(sacc[2][r], sacc[3][r]));
    #pragma unroll
    for (int o = 1; o < 16; o <<= 1) rm = fmaxf(rm, __shfl_xor(rm, o));
    float mn = fmaxf(m_i[r], rm);
    alpha[r] = __expf(m_i[r] - mn);
    float rsum = 0.f;
    #pragma unroll
    for (int j = 0; j < 4; ++j) {
      float p = __expf(sacc[j][r] - mn);
      sacc[j][r] = p; rsum += p;
    }
    #pragma unroll
    for (int o = 1; o < 16; o <<= 1) rsum += __shfl_xor(rsum, o);
    l_i[r] = l_i[r]*alpha[r] + rsum;
    m_i[r] = mn;
  }
  #pragma unroll
  for (int j = 0; j < 4; ++j)
    #pragma unroll
    for (int r = 0; r < 4; ++r)
      pw[(lg*4 + r)*ATT_PAD + j*16 + lm] = f2bf(sacc[j][r]);
  #pragma unroll
  for (int j = 0; j < 4; ++j)
    #pragma unroll
    for (int r = 0; r < 4; ++r)
      acc_o[j][r] *= alpha[r];
  #pragma unroll
  for (int s = 0; s < 2; ++s) {
    bf16x8 ap = *(const bf16x8*)&pw[lm*ATT_PAD + s*32 + lg*8];
    #pragma unroll
    for (int j = 0; j < 4; ++j)
      acc_o[j] = __builtin_amdgcn_mfma_f32_16x16x32_bf16(
          ap, *(const bf16x8*)&Vt[(j*16+lm)*ATT_PAD + s*32 + lg*8], acc_o[j], 0, 0, 0);
  }
}

__global__ __launch_bounds__(256) void attn_mfma_kernel(
    const unsigned short* __restrict__ qkvb, const unsigned short* __restrict__ vT,
    unsigned short* __restrict__ out) {
  __shared__ unsigned short Ks[64*ATT_PAD];
  __shared__ unsigned short Vt[64*ATT_PAD];
  __shared__ unsigned short Pw[4][16*ATT_PAD];

  int pr = blockIdx.x, h = blockIdx.y, b = blockIdx.z;
  int qtH = 31 - pr, qtL = pr;
  int tid = threadIdx.x;
  int w = tid >> 6, l = tid & 63;
  int lg = l >> 4, lm = l & 15;

  const size_t rs3 = 3*D_MODEL;
  const unsigned short* qb  = qkvb + (size_t)(b*SEQ)*rs3 + h*D_HEAD;
  const unsigned short* kb  = qb + D_MODEL;
  const unsigned short* vtb = vT + ((size_t)(b*N_HEADS + h)*D_HEAD)*SEQ;

  // Q A-frags for both tiles, pre-scaled by 1/8 (exact pow2)
  bf16x8 aqH[2], aqL[2];
  int qrH = qtH*64 + w*16 + lm, qrL = qtL*64 + w*16 + lm;
  #pragma unroll
  for (int s = 0; s < 2; ++s) {
    u16x8 tH = *(const u16x8*)(qb + (size_t)qrH*rs3 + s*32 + lg*8);
    u16x8 tL = *(const u16x8*)(qb + (size_t)qrL*rs3 + s*32 + lg*8);
    bf16x8 rH, rL;
    #pragma unroll
    for (int i = 0; i < 8; ++i) {
      rH[i] = (short)f2bf(bf2f(tH[i]) * 0.125f);
      rL[i] = (short)f2bf(bf2f(tL[i]) * 0.125f);
    }
    aqH[s] = rH; aqL[s] = rL;
  }

  float mH[4], lH[4], mL[4], lL[4];
  f32x4 oH[4], oL[4];
  #pragma unroll
  for (int r = 0; r < 4; ++r) { mH[r] = -INFINITY; lH[r] = 0.f; mL[r] = -INFINITY; lL[r] = 0.f; }
  #pragma unroll
  for (int j = 0; j < 4; ++j) { oH[j] = (f32x4){0.f,0.f,0.f,0.f}; oL[j] = (f32x4){0.f,0.f,0.f,0.f}; }

  unsigned short* pw = &Pw[w][0];

  for (int kt = 0; kt <= qtH; ++kt) {
    __syncthreads();
    #pragma unroll
    for (int it = 0; it < 2; ++it) {
      int idx = tid + it*256;
      int r = idx >> 3, c8 = (idx & 7)*8;
      *(u16x8*)&Ks[r*ATT_PAD + c8] = *(const u16x8*)(kb + (size_t)(kt*64 + r)*rs3 + c8);
      *(u16x8*)&Vt[r*ATT_PAD + c8] = *(const u16x8*)(vtb + (size_t)r*SEQ + kt*64 + c8);
    }
    __syncthreads();
    attn_step(aqH, mH, lH, oH, Ks, Vt, pw, lg, lm, w*16, kt == qtH);
    if (kt <= qtL)
      attn_step(aqL, mL, lL, oL, Ks, Vt, pw, lg, lm, w*16, kt == qtL);
  }

  #pragma unroll
  for (int r = 0; r < 4; ++r) {
    float invH = 1.f / lH[r], invL = 1.f / lL[r];
    int qH = qtH*64 + w*16 + lg*4 + r;
    int qL = qtL*64 + w*16 + lg*4 + r;
    #pragma unroll
    for (int j = 0; j < 4; ++j) {
      out[((size_t)(b*SEQ + qH))*D_MODEL + h*D_HEAD + j*16 + lm] = f2bf(oH[j][r]*invH);
      out[((size_t)(b*SEQ + qL))*D_MODEL + h*D_HEAD + j*16 + lm] = f2bf(oL[j][r]*invL);
    }
  }
}

extern "C" void kernel_launch(void* const* d_in, const int* in_sizes, int n_in,
                              void* d_out, int out_size, void* d_ws, size_t ws_size,
                              hipStream_t stream) {
  const float* x      = (const float*)d_in[0];
  const float* ln1_w  = (const float*)d_in[1];
  const float* ln1_b  = (const float*)d_in[2];
  const float* ln2_w  = (const float*)d_in[3];
  const float* ln2_b  = (const float*)d_in[4];
  const float* qkv_w  = (const float*)d_in[5];
  const float* o_w    = (const float*)d_in[6];
  const float* ffn_w1 = (const float*)d_in[7];
  const float* ffn_b1 = (const float*)d_in[8];
  const float* ffn_w2 = (const float*)d_in[9];
  const float* ffn_b2 = (const float*)d_in[10];
  float* out = (float*)d_out;
  float* ws  = (float*)d_ws;

  const size_t MEG = 1024*1024;
  // bf16 weights: 12M shorts contiguous at [0, 6M) floats
  unsigned short* wqkv = (unsigned short*)ws;              // 3M shorts
  unsigned short* wo   = wqkv + 3*MEG;                     // 1M
  unsigned short* w1   = wo   + 1*MEG;                     // 4M
  unsigned short* w2   = w1   + 4*MEG;                     // 4M
  unsigned short* hbf    = (unsigned short*)(ws + 6*MEG);  // [6M,8M)  h / h2
  unsigned short* attnbf = (unsigned short*)(ws + 8*MEG);  // [8M,10M)
  float* x1  = ws + 10*MEG;                                // [10M,14M)
  unsigned short* qkvb = (unsigned short*)(ws + 14*MEG);   // [14M,20M) dead after attn
  unsigned short* ffbf = (unsigned short*)(ws + 14*MEG);   // [14M,22M) reuses qkvb
  unsigned short* vT   = (unsigned short*)(ws + 22*MEG);   // [22M,24M) 4M shorts

  // 0. weights -> bf16 (single launch)
  cvt_all<<<12*MEG/1024, 256, 0, stream>>>(qkv_w, o_w, ffn_w1, ffn_w2, wqkv);
  // 1. h = LN1(x) -> bf16
  ln_kernel<<<M_TOT, 256, 0, stream>>>(x, ln1_w, ln1_b, hbf);
  // 2. qkv = h @ qkv_w.T  (4096 x 3072 x 1024) -> bf16
  gemm_mfma<0,true><<<dim3(3*D_MODEL/128, M_TOT/128), 256, 0, stream>>>(
      hbf, wqkv, nullptr, qkvb, nullptr, nullptr, M_TOT, 3*D_MODEL, D_MODEL);
  // 2.5 vT = transpose(V)
  vtrans_kernel<<<dim3(SEQ/64, N_HEADS, BATCH), 256, 0, stream>>>(qkvb, vT);
  // 3. attn = causal MHA -> bf16, paired-tile MFMA flash
  attn_mfma_kernel<<<dim3(16, N_HEADS, BATCH), 256, 0, stream>>>(qkvb, vT, attnbf);
  // 4. x1 = x + attn @ o_w.T  (4096 x 1024 x 1024) -> fp32
  gemm_mfma<2,false><<<dim3(D_MODEL/128, M_TOT/128), 256, 0, stream>>>(
      attnbf, wo, x1, nullptr, nullptr, x, M_TOT, D_MODEL, D_MODEL);
  // 5. h2 = LN2(x1) -> bf16
  ln_kernel<<<M_TOT, 256, 0, stream>>>(x1, ln2_w, ln2_b, hbf);
  // 6. ff = gelu(h2 @ ffn_w1.T + b1)  (4096 x 4096 x 1024) -> bf16
  gemm_mfma<1,true><<<dim3(FFN_DIM/128, M_TOT/128), 256, 0, stream>>>(
      hbf, w1, nullptr, ffbf, ffn_b1, nullptr, M_TOT, FFN_DIM, D_MODEL);
  // 7. out = x1 + ff @ ffn_w2.T + b2  (4096 x 1024 x 4096) -> fp32
  gemm_mfma<3,false><<<dim3(D_MODEL/128, M_TOT/128), 256, 0, stream>>>(
      ffbf, w2, out, nullptr, ffn_b2, x1, M_TOT, D_MODEL, FFN_DIM);
}

// Round 6
// 391.322 us; speedup vs baseline: 14.5419x; 1.1081x over previous
//
#include <hip/hip_runtime.h>
#include <math.h>

#define D_MODEL 1024
#define N_HEADS 16
#define D_HEAD  64
#define SEQ     2048
#define BATCH   2
#define M_TOT   (BATCH*SEQ)   // 4096
#define FFN_DIM 4096

typedef __attribute__((ext_vector_type(8))) short bf16x8;   // 8 bf16 = 4 VGPRs
typedef __attribute__((ext_vector_type(4))) float f32x4;
typedef __attribute__((ext_vector_type(8))) unsigned short u16x8;

__device__ __forceinline__ unsigned short f2bf(float f) {
  unsigned int u = __float_as_uint(f);
  return (unsigned short)((u + 0x7fffu + ((u >> 16) & 1u)) >> 16);  // RNE
}
__device__ __forceinline__ float bf2f(unsigned short s) {
  return __uint_as_float(((unsigned int)s) << 16);
}

__device__ __forceinline__ void async_ld16(void* lds, const void* g) {
  __builtin_amdgcn_global_load_lds(
      (const __attribute__((address_space(1))) unsigned int*)g,
      (__attribute__((address_space(3))) unsigned int*)lds, 16, 0, 0);
}

__device__ __forceinline__ float gelu_exact(float x) {
  return 0.5f * x * (1.f + erff(x * 0.70710678118654752f));
}

// ---------------- fp32 -> bf16 convert, all 4 weight tensors in one launch ------
__global__ __launch_bounds__(256) void cvt_all(const float* __restrict__ qkv_w,
    const float* __restrict__ o_w, const float* __restrict__ w1,
    const float* __restrict__ w2, unsigned short* __restrict__ dst) {
  const long MEGc = 1024*1024;
  long i = (long)(blockIdx.x*256 + threadIdx.x)*4;   // [0, 12M)
  const float* src; long off;
  if (i < 3*MEGc)      { src = qkv_w; off = i; }
  else if (i < 4*MEGc) { src = o_w;  off = i - 3*MEGc; }
  else if (i < 8*MEGc) { src = w1;   off = i - 4*MEGc; }
  else                 { src = w2;   off = i - 8*MEGc; }
  float4 v = *(const float4*)(src + off);
  ushort4 o = { f2bf(v.x), f2bf(v.y), f2bf(v.z), f2bf(v.w) };
  *(ushort4*)(dst + i) = o;
}

// ---------------- LayerNorm: one block (256 thr) per row of 1024, bf16 out ------
__global__ __launch_bounds__(256) void ln_kernel(const float* __restrict__ x,
    const float* __restrict__ w, const float* __restrict__ b,
    unsigned short* __restrict__ out) {
  int row = blockIdx.x;
  const float* xr = x + (size_t)row * D_MODEL;
  int c = threadIdx.x * 4;
  float4 v = *(const float4*)(xr + c);
  float s = v.x + v.y + v.z + v.w;
  __shared__ float red[4];
  #pragma unroll
  for (int o = 32; o > 0; o >>= 1) s += __shfl_down(s, o, 64);
  int wave = threadIdx.x >> 6;
  if ((threadIdx.x & 63) == 0) red[wave] = s;
  __syncthreads();
  float mean = (red[0]+red[1]+red[2]+red[3]) * (1.f/D_MODEL);
  __syncthreads();
  float d0 = v.x-mean, d1 = v.y-mean, d2 = v.z-mean, d3 = v.w-mean;
  float s2 = d0*d0 + d1*d1 + d2*d2 + d3*d3;
  #pragma unroll
  for (int o = 32; o > 0; o >>= 1) s2 += __shfl_down(s2, o, 64);
  if ((threadIdx.x & 63) == 0) red[wave] = s2;
  __syncthreads();
  float var = (red[0]+red[1]+red[2]+red[3]) * (1.f/D_MODEL);
  float rs = rsqrtf(var + 1e-5f);
  float4 wv = *(const float4*)(w + c);
  float4 bv = *(const float4*)(b + c);
  ushort4 o = { f2bf(d0*rs*wv.x + bv.x), f2bf(d1*rs*wv.y + bv.y),
                f2bf(d2*rs*wv.z + bv.z), f2bf(d3*rs*wv.w + bv.w) };
  *(ushort4*)(out + (size_t)row*D_MODEL + c) = o;
}

// ---------------- block swizzle: XCD-chunked + 8-row supertile ------------------
// nb must be divisible by 8 and nby by 8 (true for all our grids).
__device__ __forceinline__ void swizzle_block(int nbx, int nby, int& bx, int& by) {
  int nb = nbx * nby;
  int bid = blockIdx.y * nbx + blockIdx.x;
  int chunk = nb >> 3;
  int bid2 = (bid & 7) * chunk + (bid >> 3);   // contiguous region per XCD
  const int GM = 8;
  int ngroup = GM * nbx;
  int g = bid2 / ngroup, rem = bid2 % ngroup;
  by = g*GM + (rem % GM);
  bx = rem / GM;
}

// ---------------- MFMA GEMM: C[m,n] = sum_k A[m,k]*Bt[n,k] (+ epilogue) ---------
// 128xBN tile, BK=32, double-buffered global_load_lds(16B) staging,
// v_mfma_f32_16x16x32_bf16. BN=128: 4 waves in 2x2, 4x4 frags each.
// BN=64: 4 waves stacked along M (32 rows each), 2x4 frags.
// EPI: 0 = plain, 1 = gelu(x+bias), 2 = +res, 3 = +bias+res.  OBF: bf16 output.
template<int EPI, bool OBF, int BN>
__global__ __launch_bounds__(256) void gemm_mfma(
    const unsigned short* __restrict__ A, const unsigned short* __restrict__ Bt,
    float* __restrict__ Cf, unsigned short* __restrict__ Cb,
    const float* __restrict__ bias, const float* __restrict__ res,
    int M, int N, int K) {
  constexpr int BM = 128, BK = 32;
  constexpr int NI = (BN == 128) ? 4 : 2;
  __shared__ unsigned short As[2][BM*BK];
  __shared__ unsigned short Bs[2][BN*BK];
  int tid = threadIdx.x;
  int w = tid >> 6, l = tid & 63;
  int lg = l >> 4, lm = l & 15;
  int bx, by;
  swizzle_block(N/BN, M/BM, bx, by);
  int bm = by * BM, bn = bx * BN;
  int wm = (BN == 128) ? (w >> 1) * 64 : w * 32;
  int wn = (BN == 128) ? (w & 1) * 64 : 0;

  f32x4 acc[NI][4];
  #pragma unroll
  for (int i = 0; i < NI; ++i)
    #pragma unroll
    for (int j = 0; j < 4; ++j)
      acc[i][j] = (f32x4){0.f, 0.f, 0.f, 0.f};

  // staging: wave-call c fills flat ushort [c*512,(c+1)*512); lane adds l*8.
  int fa0 = (2*w+0)*512 + l*8;
  int fa1 = (2*w+1)*512 + l*8;
  const unsigned short* a0 = A + (size_t)(bm + (fa0 >> 5))*K + (fa0 & 31);
  const unsigned short* a1 = A + (size_t)(bm + (fa1 >> 5))*K + (fa1 & 31);
  const unsigned short* b0;
  const unsigned short* b1 = nullptr;
  if (BN == 128) {
    b0 = Bt + (size_t)(bn + (fa0 >> 5))*K + (fa0 & 31);
    b1 = Bt + (size_t)(bn + (fa1 >> 5))*K + (fa1 & 31);
  } else {
    int fb0 = w*512 + l*8;
    b0 = Bt + (size_t)(bn + (fb0 >> 5))*K + (fb0 & 31);
  }

  auto stage = [&](int buf, int k0) {
    async_ld16(&As[buf][(2*w+0)*512], a0 + k0);
    async_ld16(&As[buf][(2*w+1)*512], a1 + k0);
    if (BN == 128) {
      async_ld16(&Bs[buf][(2*w+0)*512], b0 + k0);
      async_ld16(&Bs[buf][(2*w+1)*512], b1 + k0);
    } else {
      async_ld16(&Bs[buf][w*512], b0 + k0);
    }
  };

  int aoff = (wm + lm)*BK + lg*8;
  int boff = (wn + lm)*BK + lg*8;

  stage(0, 0);
  int niter = K / BK;
  for (int kt = 0; kt < niter; ++kt) {
    __syncthreads();             // tile kt ready (vmcnt drain), prev compute done
    if (kt + 1 < niter) stage((kt+1) & 1, (kt+1)*BK);   // prefetch overlaps compute
    int buf = kt & 1;
    bf16x8 af[NI], bfr[4];
    #pragma unroll
    for (int i = 0; i < NI; ++i) af[i]  = *(const bf16x8*)&As[buf][aoff + i*512];
    #pragma unroll
    for (int j = 0; j < 4; ++j)  bfr[j] = *(const bf16x8*)&Bs[buf][boff + j*512];
    #pragma unroll
    for (int i = 0; i < NI; ++i)
      #pragma unroll
      for (int j = 0; j < 4; ++j)
        acc[i][j] = __builtin_amdgcn_mfma_f32_16x16x32_bf16(af[i], bfr[j], acc[i][j], 0, 0, 0);
  }

  // epilogue: C/D layout col = lane&15, row = (lane>>4)*4 + reg
  #pragma unroll
  for (int i = 0; i < NI; ++i) {
    #pragma unroll
    for (int j = 0; j < 4; ++j) {
      int col = bn + wn + j*16 + lm;
      #pragma unroll
      for (int r = 0; r < 4; ++r) {
        int row = bm + wm + i*16 + lg*4 + r;
        float v = acc[i][j][r];
        if (EPI == 1) v = gelu_exact(v + bias[col]);
        if (EPI == 2) v += res[(size_t)row*N + col];
        if (EPI == 3) v += bias[col] + res[(size_t)row*N + col];
        if (OBF) Cb[(size_t)row*N + col] = f2bf(v);
        else     Cf[(size_t)row*N + col] = v;
      }
    }
  }
}

// ---------------- V transpose: qkv V-part -> vT[b][h][d][seq] -------------------
__global__ __launch_bounds__(256) void vtrans_kernel(
    const unsigned short* __restrict__ qkvb, unsigned short* __restrict__ vT) {
  __shared__ unsigned short T[64*72];
  int nt = blockIdx.x, h = blockIdx.y, b = blockIdx.z;
  int tid = threadIdx.x;
  const unsigned short* vb = qkvb + (size_t)(b*SEQ)*(3*D_MODEL) + 2*D_MODEL + h*D_HEAD;
  #pragma unroll
  for (int it = 0; it < 2; ++it) {
    int idx = tid + it*256;
    int r = idx >> 3, c8 = (idx & 7)*8;
    *(u16x8*)&T[r*72 + c8] = *(const u16x8*)(vb + (size_t)(nt*64 + r)*(3*D_MODEL) + c8);
  }
  __syncthreads();
  unsigned short* vto = vT + ((size_t)(b*N_HEADS + h)*D_HEAD)*SEQ + nt*64;
  #pragma unroll
  for (int it = 0; it < 2; ++it) {
    int idx = tid + it*256;
    int d = idx >> 3, s8 = (idx & 7)*8;
    u16x8 o;
    #pragma unroll
    for (int i = 0; i < 8; ++i) o[i] = T[(s8+i)*72 + d];
    *(u16x8*)(vto + (size_t)d*SEQ + s8) = o;
  }
}

// ---------------- MFMA flash attention, paired q-tiles for load balance ---------
#define ATT_PAD 72
__device__ __forceinline__ void attn_step(
    const bf16x8* aq, float* m_i, float* l_i, f32x4* acc_o,
    const unsigned short* __restrict__ Ks, const unsigned short* __restrict__ Vt,
    unsigned short* __restrict__ pw, int lg, int lm, int qoff, bool diag) {
  f32x4 sacc[4];
  #pragma unroll
  for (int j = 0; j < 4; ++j) sacc[j] = (f32x4){0.f, 0.f, 0.f, 0.f};
  #pragma unroll
  for (int s = 0; s < 2; ++s)
    #pragma unroll
    for (int j = 0; j < 4; ++j)
      sacc[j] = __builtin_amdgcn_mfma_f32_16x16x32_bf16(
          aq[s], *(const bf16x8*)&Ks[(j*16+lm)*ATT_PAD + s*32 + lg*8], sacc[j], 0, 0, 0);
  if (diag) {
    #pragma unroll
    for (int j = 0; j < 4; ++j)
      #pragma unroll
      for (int r = 0; r < 4; ++r)
        if (j*16 + lm > qoff + lg*4 + r) sacc[j][r] = -INFINITY;
  }
  float alpha[4];
  #pragma unroll
  for (int r = 0; r < 4; ++r) {
    float rm = fmaxf(fmaxf(sacc[0][r], sacc[1][r]), fmaxf(sacc[2][r], sacc[3][r]));
    #pragma unroll
    for (int o = 1; o < 16; o <<= 1) rm = fmaxf(rm, __shfl_xor(rm, o));
    float mn = fmaxf(m_i[r], rm);
    alpha[r] = __expf(m_i[r] - mn);
    float rsum = 0.f;
    #pragma unroll
    for (int j = 0; j < 4; ++j) {
      float p = __expf(sacc[j][r] - mn);
      sacc[j][r] = p; rsum += p;
    }
    #pragma unroll
    for (int o = 1; o < 16; o <<= 1) rsum += __shfl_xor(rsum, o);
    l_i[r] = l_i[r]*alpha[r] + rsum;
    m_i[r] = mn;
  }
  #pragma unroll
  for (int j = 0; j < 4; ++j)
    #pragma unroll
    for (int r = 0; r < 4; ++r)
      pw[(lg*4 + r)*ATT_PAD + j*16 + lm] = f2bf(sacc[j][r]);
  #pragma unroll
  for (int j = 0; j < 4; ++j)
    #pragma unroll
    for (int r = 0; r < 4; ++r)
      acc_o[j][r] *= alpha[r];
  #pragma unroll
  for (int s = 0; s < 2; ++s) {
    bf16x8 ap = *(const bf16x8*)&pw[lm*ATT_PAD + s*32 + lg*8];
    #pragma unroll
    for (int j = 0; j < 4; ++j)
      acc_o[j] = __builtin_amdgcn_mfma_f32_16x16x32_bf16(
          ap, *(const bf16x8*)&Vt[(j*16+lm)*ATT_PAD + s*32 + lg*8], acc_o[j], 0, 0, 0);
  }
}

__global__ __launch_bounds__(256) void attn_mfma_kernel(
    const unsigned short* __restrict__ qkvb, const unsigned short* __restrict__ vT,
    unsigned short* __restrict__ out) {
  __shared__ unsigned short Ks[64*ATT_PAD];
  __shared__ unsigned short Vt[64*ATT_PAD];
  __shared__ unsigned short Pw[4][16*ATT_PAD];

  int pr = blockIdx.x, h = blockIdx.y, b = blockIdx.z;
  int qtH = 31 - pr, qtL = pr;
  int tid = threadIdx.x;
  int w = tid >> 6, l = tid & 63;
  int lg = l >> 4, lm = l & 15;

  const size_t rs3 = 3*D_MODEL;
  const unsigned short* qb  = qkvb + (size_t)(b*SEQ)*rs3 + h*D_HEAD;
  const unsigned short* kb  = qb + D_MODEL;
  const unsigned short* vtb = vT + ((size_t)(b*N_HEADS + h)*D_HEAD)*SEQ;

  bf16x8 aqH[2], aqL[2];
  int qrH = qtH*64 + w*16 + lm, qrL = qtL*64 + w*16 + lm;
  #pragma unroll
  for (int s = 0; s < 2; ++s) {
    u16x8 tH = *(const u16x8*)(qb + (size_t)qrH*rs3 + s*32 + lg*8);
    u16x8 tL = *(const u16x8*)(qb + (size_t)qrL*rs3 + s*32 + lg*8);
    bf16x8 rH, rL;
    #pragma unroll
    for (int i = 0; i < 8; ++i) {
      rH[i] = (short)f2bf(bf2f(tH[i]) * 0.125f);
      rL[i] = (short)f2bf(bf2f(tL[i]) * 0.125f);
    }
    aqH[s] = rH; aqL[s] = rL;
  }

  float mH[4], lH[4], mL[4], lL[4];
  f32x4 oH[4], oL[4];
  #pragma unroll
  for (int r = 0; r < 4; ++r) { mH[r] = -INFINITY; lH[r] = 0.f; mL[r] = -INFINITY; lL[r] = 0.f; }
  #pragma unroll
  for (int j = 0; j < 4; ++j) { oH[j] = (f32x4){0.f,0.f,0.f,0.f}; oL[j] = (f32x4){0.f,0.f,0.f,0.f}; }

  unsigned short* pw = &Pw[w][0];

  for (int kt = 0; kt <= qtH; ++kt) {
    __syncthreads();
    #pragma unroll
    for (int it = 0; it < 2; ++it) {
      int idx = tid + it*256;
      int r = idx >> 3, c8 = (idx & 7)*8;
      *(u16x8*)&Ks[r*ATT_PAD + c8] = *(const u16x8*)(kb + (size_t)(kt*64 + r)*rs3 + c8);
      *(u16x8*)&Vt[r*ATT_PAD + c8] = *(const u16x8*)(vtb + (size_t)r*SEQ + kt*64 + c8);
    }
    __syncthreads();
    attn_step(aqH, mH, lH, oH, Ks, Vt, pw, lg, lm, w*16, kt == qtH);
    if (kt <= qtL)
      attn_step(aqL, mL, lL, oL, Ks, Vt, pw, lg, lm, w*16, kt == qtL);
  }

  #pragma unroll
  for (int r = 0; r < 4; ++r) {
    float invH = 1.f / lH[r], invL = 1.f / lL[r];
    int qH = qtH*64 + w*16 + lg*4 + r;
    int qL = qtL*64 + w*16 + lg*4 + r;
    #pragma unroll
    for (int j = 0; j < 4; ++j) {
      out[((size_t)(b*SEQ + qH))*D_MODEL + h*D_HEAD + j*16 + lm] = f2bf(oH[j][r]*invH);
      out[((size_t)(b*SEQ + qL))*D_MODEL + h*D_HEAD + j*16 + lm] = f2bf(oL[j][r]*invL);
    }
  }
}

extern "C" void kernel_launch(void* const* d_in, const int* in_sizes, int n_in,
                              void* d_out, int out_size, void* d_ws, size_t ws_size,
                              hipStream_t stream) {
  const float* x      = (const float*)d_in[0];
  const float* ln1_w  = (const float*)d_in[1];
  const float* ln1_b  = (const float*)d_in[2];
  const float* ln2_w  = (const float*)d_in[3];
  const float* ln2_b  = (const float*)d_in[4];
  const float* qkv_w  = (const float*)d_in[5];
  const float* o_w    = (const float*)d_in[6];
  const float* ffn_w1 = (const float*)d_in[7];
  const float* ffn_b1 = (const float*)d_in[8];
  const float* ffn_w2 = (const float*)d_in[9];
  const float* ffn_b2 = (const float*)d_in[10];
  float* out = (float*)d_out;
  float* ws  = (float*)d_ws;

  const size_t MEG = 1024*1024;
  unsigned short* wqkv = (unsigned short*)ws;              // 3M shorts
  unsigned short* wo   = wqkv + 3*MEG;                     // 1M
  unsigned short* w1   = wo   + 1*MEG;                     // 4M
  unsigned short* w2   = w1   + 4*MEG;                     // 4M
  unsigned short* hbf    = (unsigned short*)(ws + 6*MEG);  // [6M,8M)  h / h2
  unsigned short* attnbf = (unsigned short*)(ws + 8*MEG);  // [8M,10M)
  float* x1  = ws + 10*MEG;                                // [10M,14M)
  unsigned short* qkvb = (unsigned short*)(ws + 14*MEG);   // [14M,20M) dead after attn
  unsigned short* ffbf = (unsigned short*)(ws + 14*MEG);   // [14M,22M) reuses qkvb
  unsigned short* vT   = (unsigned short*)(ws + 22*MEG);   // [22M,24M)

  // 0. weights -> bf16 (single launch)
  cvt_all<<<12*MEG/1024, 256, 0, stream>>>(qkv_w, o_w, ffn_w1, ffn_w2, wqkv);
  // 1. h = LN1(x) -> bf16
  ln_kernel<<<M_TOT, 256, 0, stream>>>(x, ln1_w, ln1_b, hbf);
  // 2. qkv = h @ qkv_w.T  (4096 x 3072 x 1024) -> bf16
  gemm_mfma<0,true,128><<<dim3(3*D_MODEL/128, M_TOT/128), 256, 0, stream>>>(
      hbf, wqkv, nullptr, qkvb, nullptr, nullptr, M_TOT, 3*D_MODEL, D_MODEL);
  // 2.5 vT = transpose(V)
  vtrans_kernel<<<dim3(SEQ/64, N_HEADS, BATCH), 256, 0, stream>>>(qkvb, vT);
  // 3. attn = causal MHA -> bf16, paired-tile MFMA flash
  attn_mfma_kernel<<<dim3(16, N_HEADS, BATCH), 256, 0, stream>>>(qkvb, vT, attnbf);
  // 4. x1 = x + attn @ o_w.T  (4096 x 1024 x 1024) -> fp32, 128x64 tiles
  gemm_mfma<2,false,64><<<dim3(D_MODEL/64, M_TOT/128), 256, 0, stream>>>(
      attnbf, wo, x1, nullptr, nullptr, x, M_TOT, D_MODEL, D_MODEL);
  // 5. h2 = LN2(x1) -> bf16
  ln_kernel<<<M_TOT, 256, 0, stream>>>(x1, ln2_w, ln2_b, hbf);
  // 6. ff = gelu(h2 @ ffn_w1.T + b1)  (4096 x 4096 x 1024) -> bf16
  gemm_mfma<1,true,128><<<dim3(FFN_DIM/128, M_TOT/128), 256, 0, stream>>>(
      hbf, w1, nullptr, ffbf, ffn_b1, nullptr, M_TOT, FFN_DIM, D_MODEL);
  // 7. out = x1 + ff @ ffn_w2.T + b2  (4096 x 1024 x 4096) -> fp32, 128x64 tiles
  gemm_mfma<3,false,64><<<dim3(D_MODEL/64, M_TOT/128), 256, 0, stream>>>(
      ffbf, w2, out, nullptr, ffn_b2, x1, M_TOT, D_MODEL, FFN_DIM);
}